// Round 15
// baseline (102.229 us; speedup 1.0000x reference)
//
#include <hip/hip_runtime.h>

typedef __bf16 bf16x8 __attribute__((ext_vector_type(8)));
typedef short short4v __attribute__((ext_vector_type(4)));
typedef short short8v __attribute__((ext_vector_type(8)));
typedef float f32x4 __attribute__((ext_vector_type(4)));
typedef __fp16 fp16x2 __attribute__((ext_vector_type(2)));

#define MFMA32 __builtin_amdgcn_mfma_f32_16x16x32_bf16
#define MFMA16K __builtin_amdgcn_mfma_f32_16x16x16bf16_1k

#define KPAD 576
#define LOG2E 1.44269504f

__device__ __forceinline__ unsigned short f2bf(float f) {
  unsigned u = __float_as_uint(f);
  u += 0x7FFFu + ((u >> 16) & 1u);
  return (unsigned short)(u >> 16);
}

__device__ __forceinline__ unsigned cvtpk_bf16(float a, float b) {
  unsigned r;
  asm("v_cvt_pk_bf16_f32 %0, %1, %2" : "=v"(r) : "v"(a), "v"(b));
  return r;  // lo = bf16(a), hi = bf16(b)
}

__device__ __forceinline__ short4v pack_bf16x4(float e0, float e1, float e2, float e3) {
  union { unsigned u[2]; short4v s; } pu;
  pu.u[0] = cvtpk_bf16(e0, e1);
  pu.u[1] = cvtpk_bf16(e2, e3);
  return pu.s;
}

__device__ __forceinline__ unsigned pk_f16(float a, float b) {
  union { fp16x2 h; unsigned u; } c;
  c.h = __builtin_amdgcn_cvt_pkrtz(a, b);
  return c.u;
}

__device__ __forceinline__ void gl_lds16(const void* g, void* l) {
  __builtin_amdgcn_global_load_lds((const __attribute__((address_space(1))) unsigned int*)g,
                                   (__attribute__((address_space(3))) unsigned int*)l, 16, 0, 0);
}

#define FENCE() asm volatile("" ::: "memory")
#define WAIT_LGKM0() do { asm volatile("s_waitcnt lgkmcnt(0)" ::: "memory"); \
                          __builtin_amdgcn_sched_barrier(0); } while (0)

// ---------------- fused pack kernel (posed | weightT | coord-head) ----------------
__global__ __launch_bounds__(256) void k_pack_all(
    const float* __restrict__ x, const float* __restrict__ cx,
    const float* __restrict__ y, const float* __restrict__ cy,
    const float* __restrict__ Wq, const float* __restrict__ Wk,
    const float* __restrict__ Wv, const float* __restrict__ Wo,
    unsigned short* __restrict__ posed, unsigned short* __restrict__ wqT,
    unsigned short* __restrict__ wkT, unsigned short* __restrict__ wvT,
    unsigned short* __restrict__ woT, unsigned short* __restrict__ qbuf,
    unsigned short* __restrict__ kbuf, const float* __restrict__ cs) {
  __shared__ unsigned short tile[32][33];
  int blk = blockIdx.x;
  if (blk < 4608) {  // posed: rows 0..4095 = (x,cx), 4096..8191 = (y,cy)
    int i = blk * 256 + threadIdx.x;  // 8192 * 144 groups of 4 cols
    int r = i / (KPAD / 4), c = (i - r * (KPAD / 4)) * 4;
    const float* feat = (r < 4096) ? x : y;
    const float* coord = (r < 4096) ? cx : cy;
    int rr = r & 4095;
    float4 v = {0.f, 0.f, 0.f, 0.f};
    if (c < 512) v = *(const float4*)(feat + (size_t)rr * 512 + c);
    else if (c == 512) {
      v.x = coord[(size_t)rr * 3];
      v.y = coord[(size_t)rr * 3 + 1];
      v.z = coord[(size_t)rr * 3 + 2];
    }
    ushort4 o = make_ushort4(f2bf(v.x), f2bf(v.y), f2bf(v.z), f2bf(v.w));
    *(ushort4*)(posed + (size_t)i * 4) = o;
  } else if (blk < 5904) {  // weight transpose: 4 matrices x 18 x 18 tiles
    int local = blk - 4608;
    int z = local / 324, rem = local % 324;
    int gy = rem / 18, gx = rem % 18;
    int nout = (z == 2) ? 576 : 512;
    if (gy * 32 >= nout) return;
    int kin = (z == 3) ? 576 : 515;
    const float* w = (z == 0) ? Wq : (z == 1) ? Wk : (z == 2) ? Wv : Wo;
    unsigned short* dst = (z == 0) ? wqT : (z == 1) ? wkT : (z == 2) ? wvT : woT;
    int kc0 = gx * 32, n0 = gy * 32;
    int tx = threadIdx.x & 31, ty = threadIdx.x >> 5;  // 32 x 8
#pragma unroll
    for (int it = 0; it < 4; ++it) {
      int kc = kc0 + ty + it * 8;
      float v = (kc < kin) ? w[(size_t)kc * nout + n0 + tx] : 0.f;
      tile[ty + it * 8][tx] = f2bf(v);
    }
    __syncthreads();
#pragma unroll
    for (int it = 0; it < 4; ++it) {
      int n = n0 + ty + it * 8;
      dst[(size_t)n * KPAD + kc0 + tx] = tile[tx][ty + it * 8];
    }
  } else {  // coord head (h=8) of q/k buffers
    int i = (blk - 5904) * 256 + threadIdx.x;  // 8192 rows * 16 groups of 4
    int rr = i >> 4, d4 = (i & 15) * 4;
    int qside = rr < 4096;
    int row = rr & 4095;
    const float* coord = qside ? cx : cy;
    unsigned short* buf = qside ? qbuf : kbuf;
    int b = row >> 11, n = row & 2047;
    ushort4 o = make_ushort4(0, 0, 0, 0);
    if (d4 == 0) {
      float sc = qside ? cs[0] * LOG2E : 1.f;
      o.x = f2bf(coord[(size_t)row * 3] * sc);
      o.y = f2bf(coord[(size_t)row * 3 + 1] * sc);
      o.z = f2bf(coord[(size_t)row * 3 + 2] * sc);
    }
    *(ushort4*)(buf + (((size_t)b * 9 + 8) * 2048 + n) * 64 + d4) = o;
  }
}

// ---------------- GEMM core: 64x64 block, 4 waves, 32x32 wave tile ----------------
template <typename EPI>
__device__ __forceinline__ void gemm_core(const unsigned short* __restrict__ A,
                                          const unsigned short* __restrict__ BT,
                                          unsigned short* smem, EPI epi) {
  const int m0 = blockIdx.x * 64;
  const int n0 = blockIdx.y * 64;
  const int tid = threadIdx.x;
  const int wave = tid >> 6, lane = tid & 63;
  const int li = lane & 15, g = lane >> 4;
  const int wm = (wave & 1) * 32;
  const int wn = (wave >> 1) * 32;
  const int swz = li & 7;

  const int srow = tid >> 3, sc = (tid & 7) ^ (srow & 7);
  const unsigned short* asrc = A + (size_t)(m0 + srow) * KPAD + sc * 8;
  const unsigned short* bsrc = BT + (size_t)(n0 + srow) * KPAD + sc * 8;

  auto stg = [&](int bufOff) {
    gl_lds16(asrc, (void*)(smem + bufOff + wave * 512));
    gl_lds16(asrc + (size_t)32 * KPAD, (void*)(smem + bufOff + 2048 + wave * 512));
    gl_lds16(bsrc, (void*)(smem + bufOff + 4096 + wave * 512));
    gl_lds16(bsrc + (size_t)32 * KPAD, (void*)(smem + bufOff + 4096 + 2048 + wave * 512));
    asrc += 64;
    bsrc += 64;
  };

  f32x4 acc[2][2];
#pragma unroll
  for (int a = 0; a < 2; ++a)
#pragma unroll
    for (int b = 0; b < 2; ++b) acc[a][b] = f32x4{0.f, 0.f, 0.f, 0.f};

  stg(0);
  FENCE();
  stg(8192);
  asm volatile("s_waitcnt vmcnt(4)" ::: "memory");
  __builtin_amdgcn_s_barrier();

  constexpr int NSTEP = KPAD / 64;  // 9
#pragma unroll
  for (int s = 0; s < NSTEP; ++s) {
    const int CB = (s & 1) * 8192;
    const unsigned short* sa = smem + CB;
    const unsigned short* sb = smem + CB + 4096;
    bf16x8 af[2][2], bf[2][2];
#pragma unroll
    for (int rg = 0; rg < 2; ++rg)
#pragma unroll
      for (int kh = 0; kh < 2; ++kh) {
        af[rg][kh] = *(const bf16x8*)(sa + (wm + rg * 16 + li) * 64 + (((kh * 4 + g) ^ swz) << 3));
        bf[rg][kh] = *(const bf16x8*)(sb + (wn + rg * 16 + li) * 64 + (((kh * 4 + g) ^ swz) << 3));
      }
    WAIT_LGKM0();
    __builtin_amdgcn_s_barrier();
    if (s + 2 < NSTEP) stg(CB);
    __builtin_amdgcn_s_setprio(1);
#pragma unroll
    for (int kh = 0; kh < 2; ++kh)
#pragma unroll
      for (int rg = 0; rg < 2; ++rg)
#pragma unroll
        for (int cg = 0; cg < 2; ++cg)
          acc[rg][cg] = MFMA32(af[rg][kh], bf[cg][kh], acc[rg][cg], 0, 0, 0);
    __builtin_amdgcn_s_setprio(0);
    if (s + 2 < NSTEP) {
      asm volatile("s_waitcnt vmcnt(4)" ::: "memory");
    } else if (s + 1 < NSTEP) {
      asm volatile("s_waitcnt vmcnt(0)" ::: "memory");
    }
    if (s + 1 < NSTEP) __builtin_amdgcn_s_barrier();
  }
  epi(acc, m0 + wm, n0 + wn, li, g);
}

// fused projection GEMM: z=0 Q (scaled), z=1 K, z=2 V (permuted vT layout)
__global__ __launch_bounds__(256) void k_proj(const unsigned short* __restrict__ px,
                                              const unsigned short* __restrict__ py,
                                              const unsigned short* __restrict__ wq,
                                              const unsigned short* __restrict__ wk,
                                              const unsigned short* __restrict__ wv,
                                              unsigned short* __restrict__ qbuf,
                                              unsigned short* __restrict__ kbuf,
                                              unsigned short* __restrict__ vtb, float qsc) {
  __shared__ unsigned short smem[16384];
  const int z = blockIdx.z;
  if (z < 2 && blockIdx.y >= 8) return;
  const unsigned short* A = (z == 0) ? px : py;
  const unsigned short* BT = (z == 0) ? wq : (z == 1) ? wk : wv;

  gemm_core(A, BT, smem, [&](f32x4 (&acc)[2][2], int mb, int nb, int li, int g) {
    if (z == 2) {  // vT permuted layout
#pragma unroll
      for (int rg = 0; rg < 2; ++rg) {
        int mr = mb + rg * 16 + 4 * g;
        int b = mr >> 11, seq0 = mr & 2047;
        int c0 = seq0 & 63;
        int npos = (seq0 & ~63) + ((c0 >> 2) & 3) * 16 + (c0 >> 4) * 4;
#pragma unroll
        for (int cg = 0; cg < 2; ++cg) {
          int col = nb + cg * 16 + li;
          int h = col >> 6, d = col & 63;
          ushort4 pk = make_ushort4(f2bf(acc[rg][cg][0]), f2bf(acc[rg][cg][1]),
                                    f2bf(acc[rg][cg][2]), f2bf(acc[rg][cg][3]));
          *(ushort4*)(vtb + (((size_t)b * 9 + h) * 64 + d) * 2048 + npos) = pk;
        }
      }
    } else {
      unsigned short* out = z ? kbuf : qbuf;
      float oscale = z ? 1.f : qsc;
#pragma unroll
      for (int rg = 0; rg < 2; ++rg) {
        int mr = mb + rg * 16 + 4 * g;
#pragma unroll
        for (int cg = 0; cg < 2; ++cg) {
          int col = nb + cg * 16 + li;
          int h = col >> 6, d = col & 63;
#pragma unroll
          for (int r = 0; r < 4; ++r) {
            int m = mr + r;
            int b = m >> 11, seq = m & 2047;
            out[(((size_t)b * 9 + h) * 2048 + seq) * 64 + d] = f2bf(acc[rg][cg][r] * oscale);
          }
        }
      }
    }
  });
}

__global__ __launch_bounds__(256) void k_gemm_out(const unsigned short* __restrict__ A,
                                                  const unsigned short* __restrict__ BT,
                                                  float* __restrict__ out, int Nout) {
  __shared__ unsigned short smem[16384];
  gemm_core(A, BT, smem, [&](f32x4 (&acc)[2][2], int mb, int nb, int li, int g) {
#pragma unroll
    for (int rg = 0; rg < 2; ++rg) {
      int mr = mb + rg * 16 + 4 * g;
#pragma unroll
      for (int cg = 0; cg < 2; ++cg) {
        int col = nb + cg * 16 + li;
#pragma unroll
        for (int r = 0; r < 4; ++r) out[(size_t)(mr + r) * Nout + col] = acc[rg][cg][r];
      }
    }
  });
}

// ---------------- flash attention: QBLK=128, 2-barrier tile loop, no-max softmax ----
// R13 kernel; only change: split-KV partial acc (pacc) stored as FP16 via
// v_cvt_pkrtz_f16_f32 (halves partial write traffic); den (pml) stays FP32.
template <int NS>
__global__ __launch_bounds__(256) void k_attn(const unsigned short* __restrict__ qb,
                                              const unsigned short* __restrict__ kb,
                                              const unsigned short* __restrict__ vt,
                                              unsigned short* __restrict__ aout,
                                              unsigned* __restrict__ pacc,
                                              float* __restrict__ pml) {
  constexpr int CH = 2048 / NS;
  constexpr int NT = CH / 64;
  constexpr int NBLK = 16 * 9 * 2 * NS;
  __shared__ unsigned short smem[16384];  // [0,8192): K dbuf ; [8192,16384): V dbuf

  int lin = blockIdx.x + 16 * (blockIdx.y + 9 * blockIdx.z);
  int nl = (lin & 7) * (NBLK / 8) + (lin >> 3);
  int bx = nl & 15;
  int rest = nl >> 4;
  int h = rest % 9;
  int z = rest / 9;
  int b = z / NS, sp = z - b * NS;

  const int wave = threadIdx.x >> 6, lane = threadIdx.x & 63;
  const int li = lane & 15, g = lane >> 4;
  const int bh = b * 9 + h;
  const int kvbase = sp * CH;
  const int swz = li & 7;

  // Q fragments (scale*log2e pre-folded): 2 groups of 16 rows
  bf16x8 qf[2][2];
#pragma unroll
  for (int u = 0; u < 2; ++u) {
    const unsigned short* qp =
        qb + ((size_t)bh * 2048 + bx * 128 + wave * 32 + u * 16 + li) * 64 + g * 8;
    qf[u][0] = *(const bf16x8*)qp;
    qf[u][1] = *(const bf16x8*)(qp + 32);
  }

  const int srow = threadIdx.x >> 3;
  const int ssc = (threadIdx.x & 7) ^ (srow & 7);
  const unsigned short* ksrc = kb + ((size_t)bh * 2048 + kvbase + srow) * 64 + ssc * 8;
  const unsigned short* vsrc = vt + ((size_t)bh * 64 + srow) * 2048 + kvbase + ssc * 8;

  auto stageK = [&](int bufOff) {
    gl_lds16(ksrc, (void*)(smem + bufOff + wave * 512));
    gl_lds16(ksrc + 32 * 64, (void*)(smem + bufOff + 2048 + wave * 512));
    ksrc += 64 * 64;
  };
  auto stageV = [&](int bufOff) {
    gl_lds16(vsrc, (void*)(smem + 8192 + bufOff + wave * 512));
    gl_lds16(vsrc + 32 * 2048, (void*)(smem + 8192 + bufOff + 2048 + wave * 512));
    vsrc += 64;
  };

  const unsigned short* kb0 = smem + li * 64 + ((g ^ swz) << 3);
  const unsigned short* kb1 = smem + li * 64 + (((4 + g) ^ swz) << 3);
  const unsigned short* vbE = smem + 8192 + li * 64 + (((2 * g) ^ swz) << 3);
  const unsigned short* vbO = smem + 8192 + li * 64 + (((2 * g + 1) ^ swz) << 3);

  float l_lane[2] = {0.f, 0.f};
  f32x4 acc[2][4];
#pragma unroll
  for (int u = 0; u < 2; ++u)
#pragma unroll
    for (int t = 0; t < 4; ++t) acc[u][t] = f32x4{0.f, 0.f, 0.f, 0.f};

  // prologue: stage tiles 0 and 1 (4 loads each per wave; queue K0V0 then K1V1)
  stageK(0);
  stageV(0);
  FENCE();
  stageK(4096);
  stageV(4096);

#pragma unroll
  for (int t = 0; t < NT; ++t) {
    const int CB = (t & 1) * 4096;

    // wait tile t's staging (own loads), then block-wide
    if (t + 1 < NT) {
      asm volatile("s_waitcnt vmcnt(4)" ::: "memory");
    } else {
      asm volatile("s_waitcnt vmcnt(0)" ::: "memory");
    }
    __builtin_amdgcn_s_barrier();  // tile t fully staged by all waves

    // ---- ALL LDS reads for tile t (K: 8 x b128, V: 8 x b128) ----
    bf16x8 kA0[4], kA1[4];
    short8v ve[4], vo[4];
#pragma unroll
    for (int tt = 0; tt < 4; ++tt) {
      kA0[tt] = *(const bf16x8*)(kb0 + CB + tt * 1024);
      kA1[tt] = *(const bf16x8*)(kb1 + CB + tt * 1024);
      ve[tt] = *(const short8v*)(vbE + CB + tt * 1024);
      vo[tt] = *(const short8v*)(vbO + CB + tt * 1024);
    }
    WAIT_LGKM0();
    __builtin_amdgcn_s_barrier();  // all waves done reading CB: safe to restage

    if (t + 2 < NT) {
      stageK(CB);
      stageV(CB);
    }

    // ---- compute, register-only, no synchronization ----
    short4v p[2][4];
#pragma unroll
    for (int u = 0; u < 2; ++u) {
      f32x4 s[4];
      __builtin_amdgcn_s_setprio(1);
#pragma unroll
      for (int tt = 0; tt < 4; ++tt) {
        f32x4 sv = {0.f, 0.f, 0.f, 0.f};
        sv = MFMA32(kA0[tt], qf[u][0], sv, 0, 0, 0);
        sv = MFMA32(kA1[tt], qf[u][1], sv, 0, 0, 0);
        s[tt] = sv;
      }
      __builtin_amdgcn_s_setprio(0);
      float ts = 0.f;
#pragma unroll
      for (int tt = 0; tt < 4; ++tt) {
        float e0 = __builtin_amdgcn_exp2f(s[tt][0]);
        float e1 = __builtin_amdgcn_exp2f(s[tt][1]);
        float e2 = __builtin_amdgcn_exp2f(s[tt][2]);
        float e3 = __builtin_amdgcn_exp2f(s[tt][3]);
        ts += (e0 + e1) + (e2 + e3);
        p[u][tt] = pack_bf16x4(e0, e1, e2, e3);
      }
      l_lane[u] += ts;
    }

    __builtin_amdgcn_s_setprio(1);
#pragma unroll
    for (int dd = 0; dd < 4; ++dd) {
      short4v v0 = __builtin_shufflevector(ve[dd], ve[dd], 0, 1, 2, 3);
      short4v v1 = __builtin_shufflevector(ve[dd], ve[dd], 4, 5, 6, 7);
      short4v v2 = __builtin_shufflevector(vo[dd], vo[dd], 0, 1, 2, 3);
      short4v v3 = __builtin_shufflevector(vo[dd], vo[dd], 4, 5, 6, 7);
#pragma unroll
      for (int u = 0; u < 2; ++u) {
        acc[u][dd] = MFMA16K(v0, p[u][0], acc[u][dd], 0, 0, 0);
        acc[u][dd] = MFMA16K(v1, p[u][1], acc[u][dd], 0, 0, 0);
        acc[u][dd] = MFMA16K(v2, p[u][2], acc[u][dd], 0, 0, 0);
        acc[u][dd] = MFMA16K(v3, p[u][3], acc[u][dd], 0, 0, 0);
      }
    }
    __builtin_amdgcn_s_setprio(0);
  }

#pragma unroll
  for (int u = 0; u < 2; ++u) {
    float lv = l_lane[u];
    lv += __shfl_xor(lv, 16);
    lv += __shfl_xor(lv, 32);
    if constexpr (NS == 1) {
      float inv = 1.f / lv;
      unsigned short* orow =
          aout + ((size_t)(b * 2048 + bx * 128 + wave * 32 + u * 16 + li)) * KPAD + h * 64;
#pragma unroll
      for (int t = 0; t < 4; ++t) {
        ushort4 pk = make_ushort4(f2bf(acc[u][t][0] * inv), f2bf(acc[u][t][1] * inv),
                                  f2bf(acc[u][t][2] * inv), f2bf(acc[u][t][3] * inv));
        *(ushort4*)(orow + t * 16 + 4 * g) = pk;
      }
    } else {
      int tile = bh * 128 + bx * 8 + wave * 2 + u;
      // fp16 partials: 1024 halfs per (tile, sp); write 4 halfs (uint2) per t
      unsigned* pa = pacc + (((size_t)tile * NS + sp) * 1024 + li * 64) / 2;
#pragma unroll
      for (int t = 0; t < 4; ++t) {
        uint2 pk2 = make_uint2(pk_f16(acc[u][t][0], acc[u][t][1]),
                               pk_f16(acc[u][t][2], acc[u][t][3]));
        *(uint2*)(pa + (t * 16 + 4 * g) / 2) = pk2;
      }
      if (g == 0) {
        float2 st = make_float2(0.f, lv);
        *(float2*)(pml + ((size_t)tile * NS + sp) * 32 + li * 2) = st;
      }
    }
  }
}

// combine split-KV partials (plain sums; fp16 num partials, fp32 den)
__global__ __launch_bounds__(256) void k_combine(const __fp16* __restrict__ pacc,
                                                 const float* __restrict__ pml,
                                                 unsigned short* __restrict__ aout, int NS) {
  int tile = blockIdx.x * 4 + (threadIdx.x >> 6);  // bh*128 + qt
  int bh = tile >> 7, qt = tile & 127;
  int b = bh / 9, h = bh - b * 9;
  int d = threadIdx.x & 63;
  for (int q = 0; q < 16; ++q) {
    const float* ml = pml + (size_t)tile * NS * 32 + q * 2;
    float num = 0.f, den = 0.f;
    const __fp16* pa = pacc + (size_t)tile * NS * 1024 + q * 64 + d;
    for (int sp = 0; sp < NS; ++sp) {
      den += ml[sp * 32 + 1];
      num += (float)pa[(size_t)sp * 1024];
    }
    aout[((size_t)(b * 2048 + qt * 16 + q)) * KPAD + h * 64 + d] = f2bf(num / den);
  }
}

// ---------------- launch ----------------

extern "C" void kernel_launch(void* const* d_in, const int* in_sizes, int n_in,
                              void* d_out, int out_size, void* d_ws, size_t ws_size,
                              hipStream_t stream) {
  const float* x  = (const float*)d_in[0];
  const float* y  = (const float*)d_in[1];
  const float* cx = (const float*)d_in[2];
  const float* cy = (const float*)d_in[3];
  const float* Wq = (const float*)d_in[4];
  const float* Wk = (const float*)d_in[5];
  const float* Wv = (const float*)d_in[6];
  const float* Wo = (const float*)d_in[7];
  const float* cs = (const float*)d_in[8];

  char* w = (char*)d_ws;
  auto take = [&](size_t bytes) {
    char* p = w;
    w += (bytes + 255) & ~(size_t)255;
    return p;
  };
  unsigned short* posed_x = (unsigned short*)take((size_t)4096 * KPAD * 2);
  unsigned short* posed_y = (unsigned short*)take((size_t)4096 * KPAD * 2);
  unsigned short* wqT = (unsigned short*)take((size_t)512 * KPAD * 2);
  unsigned short* wkT = (unsigned short*)take((size_t)512 * KPAD * 2);
  unsigned short* wvT = (unsigned short*)take((size_t)576 * KPAD * 2);
  unsigned short* woT = (unsigned short*)take((size_t)512 * KPAD * 2);
  unsigned short* qbuf = (unsigned short*)take((size_t)2 * 9 * 2048 * 64 * 2);
  unsigned short* kbuf = (unsigned short*)take((size_t)2 * 9 * 2048 * 64 * 2);
  unsigned short* vtb  = (unsigned short*)take((size_t)2 * 9 * 64 * 2048 * 2);
  unsigned short* aout = (unsigned short*)take((size_t)4096 * KPAD * 2);

  size_t base_used = (size_t)(w - (char*)d_ws);
  auto fits = [&](int ns) {
    return base_used + (size_t)2304 * ns * (1024 * 2 + 32 * 4) + 1024 <= ws_size;
  };
  int NS = fits(4) ? 4 : (fits(2) ? 2 : 1);
  unsigned* pacc = nullptr;
  float* pml = nullptr;
  if (NS > 1) {
    pacc = (unsigned*)take((size_t)2304 * NS * 1024 * 2);  // fp16 partials
    pml  = (float*)take((size_t)2304 * NS * 32 * 4);
  }

  // posed_x is the base of a contiguous [8192, KPAD] region (posed_x then posed_y)
  k_pack_all<<<6416, 256, 0, stream>>>(x, cx, y, cy, Wq, Wk, Wv, Wo,
                                       posed_x, wqT, wkT, wvT, woT, qbuf, kbuf, cs);

  const float qsc = 0.125f * LOG2E;
  k_proj<<<dim3(64, 9, 3), 256, 0, stream>>>(posed_x, posed_y, wqT, wkT, wvT,
                                             qbuf, kbuf, vtb, qsc);

  dim3 ga(16, 9, 2 * NS);
  if (NS == 4)      k_attn<4><<<ga, 256, 0, stream>>>(qbuf, kbuf, vtb, aout, pacc, pml);
  else if (NS == 2) k_attn<2><<<ga, 256, 0, stream>>>(qbuf, kbuf, vtb, aout, pacc, pml);
  else              k_attn<1><<<ga, 256, 0, stream>>>(qbuf, kbuf, vtb, aout, pacc, pml);
  if (NS > 1) k_combine<<<576, 256, 0, stream>>>((const __fp16*)pacc, pml, aout, NS);

  k_gemm_out<<<dim3(64, 8), 256, 0, stream>>>(aout, woT, (float*)d_out, 512);
}

// Round 16
// 88.007 us; speedup vs baseline: 1.1616x; 1.1616x over previous
//
#include <hip/hip_runtime.h>

typedef __bf16 bf16x8 __attribute__((ext_vector_type(8)));
typedef short short4v __attribute__((ext_vector_type(4)));
typedef short short8v __attribute__((ext_vector_type(8)));
typedef float f32x4 __attribute__((ext_vector_type(4)));

#define MFMA32 __builtin_amdgcn_mfma_f32_16x16x32_bf16
#define MFMA16K __builtin_amdgcn_mfma_f32_16x16x16bf16_1k

#define KPAD 576
#define LOG2E 1.44269504f

__device__ __forceinline__ unsigned short f2bf(float f) {
  unsigned u = __float_as_uint(f);
  u += 0x7FFFu + ((u >> 16) & 1u);
  return (unsigned short)(u >> 16);
}

__device__ __forceinline__ unsigned cvtpk_bf16(float a, float b) {
  unsigned r;
  asm("v_cvt_pk_bf16_f32 %0, %1, %2" : "=v"(r) : "v"(a), "v"(b));
  return r;  // lo = bf16(a), hi = bf16(b)
}

__device__ __forceinline__ short4v pack_bf16x4(float e0, float e1, float e2, float e3) {
  union { unsigned u[2]; short4v s; } pu;
  pu.u[0] = cvtpk_bf16(e0, e1);
  pu.u[1] = cvtpk_bf16(e2, e3);
  return pu.s;
}

__device__ __forceinline__ void gl_lds16(const void* g, void* l) {
  __builtin_amdgcn_global_load_lds((const __attribute__((address_space(1))) unsigned int*)g,
                                   (__attribute__((address_space(3))) unsigned int*)l, 16, 0, 0);
}

#define FENCE() asm volatile("" ::: "memory")
#define WAIT_LGKM0() do { asm volatile("s_waitcnt lgkmcnt(0)" ::: "memory"); \
                          __builtin_amdgcn_sched_barrier(0); } while (0)

// ---------------- fused pack kernel (posed | weightT | coord-head) ----------------
__global__ __launch_bounds__(256) void k_pack_all(
    const float* __restrict__ x, const float* __restrict__ cx,
    const float* __restrict__ y, const float* __restrict__ cy,
    const float* __restrict__ Wq, const float* __restrict__ Wk,
    const float* __restrict__ Wv, const float* __restrict__ Wo,
    unsigned short* __restrict__ posed, unsigned short* __restrict__ wqT,
    unsigned short* __restrict__ wkT, unsigned short* __restrict__ wvT,
    unsigned short* __restrict__ woT, unsigned short* __restrict__ qbuf,
    unsigned short* __restrict__ kbuf, const float* __restrict__ cs) {
  __shared__ unsigned short tile[32][33];
  int blk = blockIdx.x;
  if (blk < 4608) {  // posed: rows 0..4095 = (x,cx), 4096..8191 = (y,cy)
    int i = blk * 256 + threadIdx.x;  // 8192 * 144 groups of 4 cols
    int r = i / (KPAD / 4), c = (i - r * (KPAD / 4)) * 4;
    const float* feat = (r < 4096) ? x : y;
    const float* coord = (r < 4096) ? cx : cy;
    int rr = r & 4095;
    float4 v = {0.f, 0.f, 0.f, 0.f};
    if (c < 512) v = *(const float4*)(feat + (size_t)rr * 512 + c);
    else if (c == 512) {
      v.x = coord[(size_t)rr * 3];
      v.y = coord[(size_t)rr * 3 + 1];
      v.z = coord[(size_t)rr * 3 + 2];
    }
    ushort4 o = make_ushort4(f2bf(v.x), f2bf(v.y), f2bf(v.z), f2bf(v.w));
    *(ushort4*)(posed + (size_t)i * 4) = o;
  } else if (blk < 5904) {  // weight transpose: 4 matrices x 18 x 18 tiles
    int local = blk - 4608;
    int z = local / 324, rem = local % 324;
    int gy = rem / 18, gx = rem % 18;
    int nout = (z == 2) ? 576 : 512;
    if (gy * 32 >= nout) return;
    int kin = (z == 3) ? 576 : 515;
    const float* w = (z == 0) ? Wq : (z == 1) ? Wk : (z == 2) ? Wv : Wo;
    unsigned short* dst = (z == 0) ? wqT : (z == 1) ? wkT : (z == 2) ? wvT : woT;
    int kc0 = gx * 32, n0 = gy * 32;
    int tx = threadIdx.x & 31, ty = threadIdx.x >> 5;  // 32 x 8
#pragma unroll
    for (int it = 0; it < 4; ++it) {
      int kc = kc0 + ty + it * 8;
      float v = (kc < kin) ? w[(size_t)kc * nout + n0 + tx] : 0.f;
      tile[ty + it * 8][tx] = f2bf(v);
    }
    __syncthreads();
#pragma unroll
    for (int it = 0; it < 4; ++it) {
      int n = n0 + ty + it * 8;
      dst[(size_t)n * KPAD + kc0 + tx] = tile[tx][ty + it * 8];
    }
  } else {  // coord head (h=8) of q/k buffers
    int i = (blk - 5904) * 256 + threadIdx.x;  // 8192 rows * 16 groups of 4
    int rr = i >> 4, d4 = (i & 15) * 4;
    int qside = rr < 4096;
    int row = rr & 4095;
    const float* coord = qside ? cx : cy;
    unsigned short* buf = qside ? qbuf : kbuf;
    int b = row >> 11, n = row & 2047;
    ushort4 o = make_ushort4(0, 0, 0, 0);
    if (d4 == 0) {
      float sc = qside ? cs[0] * LOG2E : 1.f;
      o.x = f2bf(coord[(size_t)row * 3] * sc);
      o.y = f2bf(coord[(size_t)row * 3 + 1] * sc);
      o.z = f2bf(coord[(size_t)row * 3 + 2] * sc);
    }
    *(ushort4*)(buf + (((size_t)b * 9 + 8) * 2048 + n) * 64 + d4) = o;
  }
}

// ---------------- GEMM core: 64x64 block, 4 waves, 32x32 wave tile ----------------
template <typename EPI>
__device__ __forceinline__ void gemm_core(const unsigned short* __restrict__ A,
                                          const unsigned short* __restrict__ BT,
                                          unsigned short* smem, EPI epi) {
  const int m0 = blockIdx.x * 64;
  const int n0 = blockIdx.y * 64;
  const int tid = threadIdx.x;
  const int wave = tid >> 6, lane = tid & 63;
  const int li = lane & 15, g = lane >> 4;
  const int wm = (wave & 1) * 32;
  const int wn = (wave >> 1) * 32;
  const int swz = li & 7;

  const int srow = tid >> 3, sc = (tid & 7) ^ (srow & 7);
  const unsigned short* asrc = A + (size_t)(m0 + srow) * KPAD + sc * 8;
  const unsigned short* bsrc = BT + (size_t)(n0 + srow) * KPAD + sc * 8;

  auto stg = [&](int bufOff) {
    gl_lds16(asrc, (void*)(smem + bufOff + wave * 512));
    gl_lds16(asrc + (size_t)32 * KPAD, (void*)(smem + bufOff + 2048 + wave * 512));
    gl_lds16(bsrc, (void*)(smem + bufOff + 4096 + wave * 512));
    gl_lds16(bsrc + (size_t)32 * KPAD, (void*)(smem + bufOff + 4096 + 2048 + wave * 512));
    asrc += 64;
    bsrc += 64;
  };

  f32x4 acc[2][2];
#pragma unroll
  for (int a = 0; a < 2; ++a)
#pragma unroll
    for (int b = 0; b < 2; ++b) acc[a][b] = f32x4{0.f, 0.f, 0.f, 0.f};

  stg(0);
  FENCE();
  stg(8192);
  asm volatile("s_waitcnt vmcnt(4)" ::: "memory");
  __builtin_amdgcn_s_barrier();

  constexpr int NSTEP = KPAD / 64;  // 9
#pragma unroll
  for (int s = 0; s < NSTEP; ++s) {
    const int CB = (s & 1) * 8192;
    const unsigned short* sa = smem + CB;
    const unsigned short* sb = smem + CB + 4096;
    bf16x8 af[2][2], bf[2][2];
#pragma unroll
    for (int rg = 0; rg < 2; ++rg)
#pragma unroll
      for (int kh = 0; kh < 2; ++kh) {
        af[rg][kh] = *(const bf16x8*)(sa + (wm + rg * 16 + li) * 64 + (((kh * 4 + g) ^ swz) << 3));
        bf[rg][kh] = *(const bf16x8*)(sb + (wn + rg * 16 + li) * 64 + (((kh * 4 + g) ^ swz) << 3));
      }
    WAIT_LGKM0();
    __builtin_amdgcn_s_barrier();
    if (s + 2 < NSTEP) stg(CB);
    __builtin_amdgcn_s_setprio(1);
#pragma unroll
    for (int kh = 0; kh < 2; ++kh)
#pragma unroll
      for (int rg = 0; rg < 2; ++rg)
#pragma unroll
        for (int cg = 0; cg < 2; ++cg)
          acc[rg][cg] = MFMA32(af[rg][kh], bf[cg][kh], acc[rg][cg], 0, 0, 0);
    __builtin_amdgcn_s_setprio(0);
    if (s + 2 < NSTEP) {
      asm volatile("s_waitcnt vmcnt(4)" ::: "memory");
    } else if (s + 1 < NSTEP) {
      asm volatile("s_waitcnt vmcnt(0)" ::: "memory");
    }
    if (s + 1 < NSTEP) __builtin_amdgcn_s_barrier();
  }
  epi(acc, m0 + wm, n0 + wn, li, g);
}

// fused projection GEMM: z=0 Q (scaled), z=1 K, z=2 V (permuted vT layout)
__global__ __launch_bounds__(256) void k_proj(const unsigned short* __restrict__ px,
                                              const unsigned short* __restrict__ py,
                                              const unsigned short* __restrict__ wq,
                                              const unsigned short* __restrict__ wk,
                                              const unsigned short* __restrict__ wv,
                                              unsigned short* __restrict__ qbuf,
                                              unsigned short* __restrict__ kbuf,
                                              unsigned short* __restrict__ vtb, float qsc) {
  __shared__ unsigned short smem[16384];
  const int z = blockIdx.z;
  if (z < 2 && blockIdx.y >= 8) return;
  const unsigned short* A = (z == 0) ? px : py;
  const unsigned short* BT = (z == 0) ? wq : (z == 1) ? wk : wv;

  gemm_core(A, BT, smem, [&](f32x4 (&acc)[2][2], int mb, int nb, int li, int g) {
    if (z == 2) {  // vT permuted layout
#pragma unroll
      for (int rg = 0; rg < 2; ++rg) {
        int mr = mb + rg * 16 + 4 * g;
        int b = mr >> 11, seq0 = mr & 2047;
        int c0 = seq0 & 63;
        int npos = (seq0 & ~63) + ((c0 >> 2) & 3) * 16 + (c0 >> 4) * 4;
#pragma unroll
        for (int cg = 0; cg < 2; ++cg) {
          int col = nb + cg * 16 + li;
          int h = col >> 6, d = col & 63;
          ushort4 pk = make_ushort4(f2bf(acc[rg][cg][0]), f2bf(acc[rg][cg][1]),
                                    f2bf(acc[rg][cg][2]), f2bf(acc[rg][cg][3]));
          *(ushort4*)(vtb + (((size_t)b * 9 + h) * 64 + d) * 2048 + npos) = pk;
        }
      }
    } else {
      unsigned short* out = z ? kbuf : qbuf;
      float oscale = z ? 1.f : qsc;
#pragma unroll
      for (int rg = 0; rg < 2; ++rg) {
        int mr = mb + rg * 16 + 4 * g;
#pragma unroll
        for (int cg = 0; cg < 2; ++cg) {
          int col = nb + cg * 16 + li;
          int h = col >> 6, d = col & 63;
#pragma unroll
          for (int r = 0; r < 4; ++r) {
            int m = mr + r;
            int b = m >> 11, seq = m & 2047;
            out[(((size_t)b * 9 + h) * 2048 + seq) * 64 + d] = f2bf(acc[rg][cg][r] * oscale);
          }
        }
      }
    }
  });
}

__global__ __launch_bounds__(256) void k_gemm_out(const unsigned short* __restrict__ A,
                                                  const unsigned short* __restrict__ BT,
                                                  float* __restrict__ out, int Nout) {
  __shared__ unsigned short smem[16384];
  gemm_core(A, BT, smem, [&](f32x4 (&acc)[2][2], int mb, int nb, int li, int g) {
#pragma unroll
    for (int rg = 0; rg < 2; ++rg) {
      int mr = mb + rg * 16 + 4 * g;
#pragma unroll
      for (int cg = 0; cg < 2; ++cg) {
        int col = nb + cg * 16 + li;
#pragma unroll
        for (int r = 0; r < 4; ++r) out[(size_t)(mr + r) * Nout + col] = acc[rg][cg][r];
      }
    }
  });
}

// ---------------- flash attention: QBLK=128, 4 waves x 2 u-groups, no-max softmax ----
// R12's exact kernel (best measured: 87.9 us total): counted-vmcnt pipeline,
// per-u transient QK/softmax, no-max softmax (shift-invariant; scale*log2e in Q),
// fp32 partials (VGPR ~128 = 4 waves/SIMD; fp16 partials crossed the cliff, R15).
template <int NS>
__global__ __launch_bounds__(256) void k_attn(const unsigned short* __restrict__ qb,
                                              const unsigned short* __restrict__ kb,
                                              const unsigned short* __restrict__ vt,
                                              unsigned short* __restrict__ aout,
                                              float* __restrict__ pacc,
                                              float* __restrict__ pml) {
  constexpr int CH = 2048 / NS;
  constexpr int NT = CH / 64;
  constexpr int NBLK = 16 * 9 * 2 * NS;
  __shared__ unsigned short smem[16384];  // [0,8192): K dbuf ; [8192,16384): V dbuf

  int lin = blockIdx.x + 16 * (blockIdx.y + 9 * blockIdx.z);
  int nl = (lin & 7) * (NBLK / 8) + (lin >> 3);
  int bx = nl & 15;
  int rest = nl >> 4;
  int h = rest % 9;
  int z = rest / 9;
  int b = z / NS, sp = z - b * NS;

  const int wave = threadIdx.x >> 6, lane = threadIdx.x & 63;
  const int li = lane & 15, g = lane >> 4;
  const int bh = b * 9 + h;
  const int kvbase = sp * CH;
  const int swz = li & 7;

  // Q fragments (scale*log2e pre-folded): 2 groups of 16 rows
  bf16x8 qf[2][2];
#pragma unroll
  for (int u = 0; u < 2; ++u) {
    const unsigned short* qp =
        qb + ((size_t)bh * 2048 + bx * 128 + wave * 32 + u * 16 + li) * 64 + g * 8;
    qf[u][0] = *(const bf16x8*)qp;
    qf[u][1] = *(const bf16x8*)(qp + 32);
  }

  const int srow = threadIdx.x >> 3;
  const int ssc = (threadIdx.x & 7) ^ (srow & 7);
  const unsigned short* ksrc = kb + ((size_t)bh * 2048 + kvbase + srow) * 64 + ssc * 8;
  const unsigned short* vsrc = vt + ((size_t)bh * 64 + srow) * 2048 + kvbase + ssc * 8;

  auto stageK = [&](int bufOff) {
    gl_lds16(ksrc, (void*)(smem + bufOff + wave * 512));
    gl_lds16(ksrc + 32 * 64, (void*)(smem + bufOff + 2048 + wave * 512));
    ksrc += 64 * 64;
  };
  auto stageV = [&](int bufOff) {
    gl_lds16(vsrc, (void*)(smem + 8192 + bufOff + wave * 512));
    gl_lds16(vsrc + 32 * 2048, (void*)(smem + 8192 + bufOff + 2048 + wave * 512));
    vsrc += 64;
  };

  const unsigned short* kb0 = smem + li * 64 + ((g ^ swz) << 3);
  const unsigned short* kb1 = smem + li * 64 + (((4 + g) ^ swz) << 3);
  const unsigned short* vbE = smem + 8192 + li * 64 + (((2 * g) ^ swz) << 3);
  const unsigned short* vbO = smem + 8192 + li * 64 + (((2 * g + 1) ^ swz) << 3);

  float l_lane[2] = {0.f, 0.f};
  f32x4 acc[2][4];
#pragma unroll
  for (int u = 0; u < 2; ++u)
#pragma unroll
    for (int t = 0; t < 4; ++t) acc[u][t] = f32x4{0.f, 0.f, 0.f, 0.f};

  // prologue: 2 tiles in flight; vmcnt queue = K0,V0,K1,V1
  stageK(0);
  stageV(0);
  FENCE();
  stageK(4096);
  stageV(4096);
  asm volatile("s_waitcnt vmcnt(4)" ::: "memory");
  __builtin_amdgcn_s_barrier();

#pragma unroll
  for (int t = 0; t < NT; ++t) {
    const int CB = (t & 1) * 4096;

    // ---- K frags once per tile, then per-u QK + no-max softmax ----
    bf16x8 kA0[4], kA1[4];
#pragma unroll
    for (int tt = 0; tt < 4; ++tt) {
      kA0[tt] = *(const bf16x8*)(kb0 + CB + tt * 1024);
      kA1[tt] = *(const bf16x8*)(kb1 + CB + tt * 1024);
    }
    short4v p[2][4];
#pragma unroll
    for (int u = 0; u < 2; ++u) {
      f32x4 s[4];
      __builtin_amdgcn_s_setprio(1);
#pragma unroll
      for (int tt = 0; tt < 4; ++tt) {
        f32x4 sv = {0.f, 0.f, 0.f, 0.f};
        sv = MFMA32(kA0[tt], qf[u][0], sv, 0, 0, 0);
        sv = MFMA32(kA1[tt], qf[u][1], sv, 0, 0, 0);
        s[tt] = sv;
      }
      __builtin_amdgcn_s_setprio(0);
      float ts = 0.f;
#pragma unroll
      for (int tt = 0; tt < 4; ++tt) {
        float e0 = __builtin_amdgcn_exp2f(s[tt][0]);
        float e1 = __builtin_amdgcn_exp2f(s[tt][1]);
        float e2 = __builtin_amdgcn_exp2f(s[tt][2]);
        float e3 = __builtin_amdgcn_exp2f(s[tt][3]);
        ts += (e0 + e1) + (e2 + e3);
        p[u][tt] = pack_bf16x4(e0, e1, e2, e3);
      }
      l_lane[u] += ts;
    }
    WAIT_LGKM0();
    __builtin_amdgcn_s_barrier();  // all waves done reading K[CB]
    if (t + 2 < NT) stageK(CB);

    // ---- PV (permuted V layout) ----
    __builtin_amdgcn_s_setprio(1);
#pragma unroll
    for (int dd = 0; dd < 4; ++dd) {
      short8v ve = *(const short8v*)(vbE + CB + dd * 1024);
      short8v vo = *(const short8v*)(vbO + CB + dd * 1024);
      short4v v0 = __builtin_shufflevector(ve, ve, 0, 1, 2, 3);
      short4v v1 = __builtin_shufflevector(ve, ve, 4, 5, 6, 7);
      short4v v2 = __builtin_shufflevector(vo, vo, 0, 1, 2, 3);
      short4v v3 = __builtin_shufflevector(vo, vo, 4, 5, 6, 7);
#pragma unroll
      for (int u = 0; u < 2; ++u) {
        acc[u][dd] = MFMA16K(v0, p[u][0], acc[u][dd], 0, 0, 0);
        acc[u][dd] = MFMA16K(v1, p[u][1], acc[u][dd], 0, 0, 0);
        acc[u][dd] = MFMA16K(v2, p[u][2], acc[u][dd], 0, 0, 0);
        acc[u][dd] = MFMA16K(v3, p[u][3], acc[u][dd], 0, 0, 0);
      }
    }
    __builtin_amdgcn_s_setprio(0);
    WAIT_LGKM0();
    __builtin_amdgcn_s_barrier();  // all waves done reading V[CB]
    if (t + 2 < NT) stageV(CB);

    if (t + 2 < NT) {
      asm volatile("s_waitcnt vmcnt(4)" ::: "memory");
    } else if (t + 1 < NT) {
      asm volatile("s_waitcnt vmcnt(0)" ::: "memory");
    }
    if (t + 1 < NT) __builtin_amdgcn_s_barrier();
  }

#pragma unroll
  for (int u = 0; u < 2; ++u) {
    float lv = l_lane[u];
    lv += __shfl_xor(lv, 16);
    lv += __shfl_xor(lv, 32);
    if constexpr (NS == 1) {
      float inv = 1.f / lv;
      unsigned short* orow =
          aout + ((size_t)(b * 2048 + bx * 128 + wave * 32 + u * 16 + li)) * KPAD + h * 64;
#pragma unroll
      for (int t = 0; t < 4; ++t) {
        ushort4 pk = make_ushort4(f2bf(acc[u][t][0] * inv), f2bf(acc[u][t][1] * inv),
                                  f2bf(acc[u][t][2] * inv), f2bf(acc[u][t][3] * inv));
        *(ushort4*)(orow + t * 16 + 4 * g) = pk;
      }
    } else {
      int tile = bh * 128 + bx * 8 + wave * 2 + u;
      float* pa = pacc + ((size_t)tile * NS + sp) * 1024 + li * 64;
#pragma unroll
      for (int t = 0; t < 4; ++t) *(f32x4*)(pa + t * 16 + 4 * g) = acc[u][t];
      if (g == 0) {
        float2 st = make_float2(0.f, lv);
        *(float2*)(pml + ((size_t)tile * NS + sp) * 32 + li * 2) = st;
      }
    }
  }
}

// combine split-KV partials (plain sums; partials are exact softmax num/den)
__global__ __launch_bounds__(256) void k_combine(const float* __restrict__ pacc,
                                                 const float* __restrict__ pml,
                                                 unsigned short* __restrict__ aout, int NS) {
  int tile = blockIdx.x * 4 + (threadIdx.x >> 6);  // bh*128 + qt
  int bh = tile >> 7, qt = tile & 127;
  int b = bh / 9, h = bh - b * 9;
  int d = threadIdx.x & 63;
  for (int q = 0; q < 16; ++q) {
    const float* ml = pml + (size_t)tile * NS * 32 + q * 2;
    float num = 0.f, den = 0.f;
    const float* pa = pacc + (size_t)tile * NS * 1024 + q * 64 + d;
    for (int sp = 0; sp < NS; ++sp) {
      den += ml[sp * 32 + 1];
      num += pa[(size_t)sp * 1024];
    }
    aout[((size_t)(b * 2048 + qt * 16 + q)) * KPAD + h * 64 + d] = f2bf(num / den);
  }
}

// ---------------- launch ----------------

extern "C" void kernel_launch(void* const* d_in, const int* in_sizes, int n_in,
                              void* d_out, int out_size, void* d_ws, size_t ws_size,
                              hipStream_t stream) {
  const float* x  = (const float*)d_in[0];
  const float* y  = (const float*)d_in[1];
  const float* cx = (const float*)d_in[2];
  const float* cy = (const float*)d_in[3];
  const float* Wq = (const float*)d_in[4];
  const float* Wk = (const float*)d_in[5];
  const float* Wv = (const float*)d_in[6];
  const float* Wo = (const float*)d_in[7];
  const float* cs = (const float*)d_in[8];

  char* w = (char*)d_ws;
  auto take = [&](size_t bytes) {
    char* p = w;
    w += (bytes + 255) & ~(size_t)255;
    return p;
  };
  unsigned short* posed_x = (unsigned short*)take((size_t)4096 * KPAD * 2);
  unsigned short* posed_y = (unsigned short*)take((size_t)4096 * KPAD * 2);
  unsigned short* wqT = (unsigned short*)take((size_t)512 * KPAD * 2);
  unsigned short* wkT = (unsigned short*)take((size_t)512 * KPAD * 2);
  unsigned short* wvT = (unsigned short*)take((size_t)576 * KPAD * 2);
  unsigned short* woT = (unsigned short*)take((size_t)512 * KPAD * 2);
  unsigned short* qbuf = (unsigned short*)take((size_t)2 * 9 * 2048 * 64 * 2);
  unsigned short* kbuf = (unsigned short*)take((size_t)2 * 9 * 2048 * 64 * 2);
  unsigned short* vtb  = (unsigned short*)take((size_t)2 * 9 * 64 * 2048 * 2);
  unsigned short* aout = (unsigned short*)take((size_t)4096 * KPAD * 2);

  size_t base_used = (size_t)(w - (char*)d_ws);
  auto fits = [&](int ns) {
    return base_used + (size_t)2304 * ns * (1024 + 32) * 4 + 1024 <= ws_size;
  };
  int NS = fits(4) ? 4 : (fits(2) ? 2 : 1);
  float* pacc = nullptr;
  float* pml = nullptr;
  if (NS > 1) {
    pacc = (float*)take((size_t)2304 * NS * 1024 * 4);
    pml  = (float*)take((size_t)2304 * NS * 32 * 4);
  }

  // posed_x is the base of a contiguous [8192, KPAD] region (posed_x then posed_y)
  k_pack_all<<<6416, 256, 0, stream>>>(x, cx, y, cy, Wq, Wk, Wv, Wo,
                                       posed_x, wqT, wkT, wvT, woT, qbuf, kbuf, cs);

  const float qsc = 0.125f * LOG2E;
  k_proj<<<dim3(64, 9, 3), 256, 0, stream>>>(posed_x, posed_y, wqT, wkT, wvT,
                                             qbuf, kbuf, vtb, qsc);

  dim3 ga(16, 9, 2 * NS);
  if (NS == 4)      k_attn<4><<<ga, 256, 0, stream>>>(qbuf, kbuf, vtb, aout, pacc, pml);
  else if (NS == 2) k_attn<2><<<ga, 256, 0, stream>>>(qbuf, kbuf, vtb, aout, pacc, pml);
  else              k_attn<1><<<ga, 256, 0, stream>>>(qbuf, kbuf, vtb, aout, pacc, pml);
  if (NS > 1) k_combine<<<576, 256, 0, stream>>>(pacc, pml, aout, NS);

  k_gemm_out<<<dim3(64, 8), 256, 0, stream>>>(aout, woT, (float*)d_out, 512);
}

// Round 17
// 87.738 us; speedup vs baseline: 1.1652x; 1.0031x over previous
//
#include <hip/hip_runtime.h>

typedef __bf16 bf16x8 __attribute__((ext_vector_type(8)));
typedef short short4v __attribute__((ext_vector_type(4)));
typedef short short8v __attribute__((ext_vector_type(8)));
typedef float f32x4 __attribute__((ext_vector_type(4)));

#define MFMA32 __builtin_amdgcn_mfma_f32_16x16x32_bf16
#define MFMA16K __builtin_amdgcn_mfma_f32_16x16x16bf16_1k

#define KPAD 576
#define LOG2E 1.44269504f

__device__ __forceinline__ unsigned short f2bf(float f) {
  unsigned u = __float_as_uint(f);
  u += 0x7FFFu + ((u >> 16) & 1u);
  return (unsigned short)(u >> 16);
}

__device__ __forceinline__ unsigned cvtpk_bf16(float a, float b) {
  unsigned r;
  asm("v_cvt_pk_bf16_f32 %0, %1, %2" : "=v"(r) : "v"(a), "v"(b));
  return r;  // lo = bf16(a), hi = bf16(b)
}

__device__ __forceinline__ short4v pack_bf16x4(float e0, float e1, float e2, float e3) {
  union { unsigned u[2]; short4v s; } pu;
  pu.u[0] = cvtpk_bf16(e0, e1);
  pu.u[1] = cvtpk_bf16(e2, e3);
  return pu.s;
}

__device__ __forceinline__ void gl_lds16(const void* g, void* l) {
  __builtin_amdgcn_global_load_lds((const __attribute__((address_space(1))) unsigned int*)g,
                                   (__attribute__((address_space(3))) unsigned int*)l, 16, 0, 0);
}

#define FENCE() asm volatile("" ::: "memory")
#define WAIT_LGKM0() do { asm volatile("s_waitcnt lgkmcnt(0)" ::: "memory"); \
                          __builtin_amdgcn_sched_barrier(0); } while (0)

// ---------------- fused pack kernel (posed | weightT | coord-head) ----------------
__global__ __launch_bounds__(256) void k_pack_all(
    const float* __restrict__ x, const float* __restrict__ cx,
    const float* __restrict__ y, const float* __restrict__ cy,
    const float* __restrict__ Wq, const float* __restrict__ Wk,
    const float* __restrict__ Wv, const float* __restrict__ Wo,
    unsigned short* __restrict__ posed, unsigned short* __restrict__ wqT,
    unsigned short* __restrict__ wkT, unsigned short* __restrict__ wvT,
    unsigned short* __restrict__ woT, unsigned short* __restrict__ qbuf,
    unsigned short* __restrict__ kbuf, const float* __restrict__ cs) {
  __shared__ unsigned short tile[32][33];
  int blk = blockIdx.x;
  if (blk < 4608) {  // posed: rows 0..4095 = (x,cx), 4096..8191 = (y,cy)
    int i = blk * 256 + threadIdx.x;  // 8192 * 144 groups of 4 cols
    int r = i / (KPAD / 4), c = (i - r * (KPAD / 4)) * 4;
    const float* feat = (r < 4096) ? x : y;
    const float* coord = (r < 4096) ? cx : cy;
    int rr = r & 4095;
    float4 v = {0.f, 0.f, 0.f, 0.f};
    if (c < 512) v = *(const float4*)(feat + (size_t)rr * 512 + c);
    else if (c == 512) {
      v.x = coord[(size_t)rr * 3];
      v.y = coord[(size_t)rr * 3 + 1];
      v.z = coord[(size_t)rr * 3 + 2];
    }
    ushort4 o = make_ushort4(f2bf(v.x), f2bf(v.y), f2bf(v.z), f2bf(v.w));
    *(ushort4*)(posed + (size_t)i * 4) = o;
  } else if (blk < 5904) {  // weight transpose: 4 matrices x 18 x 18 tiles
    int local = blk - 4608;
    int z = local / 324, rem = local % 324;
    int gy = rem / 18, gx = rem % 18;
    int nout = (z == 2) ? 576 : 512;
    if (gy * 32 >= nout) return;
    int kin = (z == 3) ? 576 : 515;
    const float* w = (z == 0) ? Wq : (z == 1) ? Wk : (z == 2) ? Wv : Wo;
    unsigned short* dst = (z == 0) ? wqT : (z == 1) ? wkT : (z == 2) ? wvT : woT;
    int kc0 = gx * 32, n0 = gy * 32;
    int tx = threadIdx.x & 31, ty = threadIdx.x >> 5;  // 32 x 8
#pragma unroll
    for (int it = 0; it < 4; ++it) {
      int kc = kc0 + ty + it * 8;
      float v = (kc < kin) ? w[(size_t)kc * nout + n0 + tx] : 0.f;
      tile[ty + it * 8][tx] = f2bf(v);
    }
    __syncthreads();
#pragma unroll
    for (int it = 0; it < 4; ++it) {
      int n = n0 + ty + it * 8;
      dst[(size_t)n * KPAD + kc0 + tx] = tile[tx][ty + it * 8];
    }
  } else {  // coord head (h=8) of q/k buffers
    int i = (blk - 5904) * 256 + threadIdx.x;  // 8192 rows * 16 groups of 4
    int rr = i >> 4, d4 = (i & 15) * 4;
    int qside = rr < 4096;
    int row = rr & 4095;
    const float* coord = qside ? cx : cy;
    unsigned short* buf = qside ? qbuf : kbuf;
    int b = row >> 11, n = row & 2047;
    ushort4 o = make_ushort4(0, 0, 0, 0);
    if (d4 == 0) {
      float sc = qside ? cs[0] * LOG2E : 1.f;
      o.x = f2bf(coord[(size_t)row * 3] * sc);
      o.y = f2bf(coord[(size_t)row * 3 + 1] * sc);
      o.z = f2bf(coord[(size_t)row * 3 + 2] * sc);
    }
    *(ushort4*)(buf + (((size_t)b * 9 + 8) * 2048 + n) * 64 + d4) = o;
  }
}

// ---------------- GEMM core: 64x64 block, 4 waves, 32x32 wave tile ----------------
// m0/n0 passed in (callers apply XCD-bijective block remap).
template <typename EPI>
__device__ __forceinline__ void gemm_core(const unsigned short* __restrict__ A,
                                          const unsigned short* __restrict__ BT,
                                          unsigned short* smem, int m0, int n0, EPI epi) {
  const int tid = threadIdx.x;
  const int wave = tid >> 6, lane = tid & 63;
  const int li = lane & 15, g = lane >> 4;
  const int wm = (wave & 1) * 32;
  const int wn = (wave >> 1) * 32;
  const int swz = li & 7;

  const int srow = tid >> 3, sc = (tid & 7) ^ (srow & 7);
  const unsigned short* asrc = A + (size_t)(m0 + srow) * KPAD + sc * 8;
  const unsigned short* bsrc = BT + (size_t)(n0 + srow) * KPAD + sc * 8;

  auto stg = [&](int bufOff) {
    gl_lds16(asrc, (void*)(smem + bufOff + wave * 512));
    gl_lds16(asrc + (size_t)32 * KPAD, (void*)(smem + bufOff + 2048 + wave * 512));
    gl_lds16(bsrc, (void*)(smem + bufOff + 4096 + wave * 512));
    gl_lds16(bsrc + (size_t)32 * KPAD, (void*)(smem + bufOff + 4096 + 2048 + wave * 512));
    asrc += 64;
    bsrc += 64;
  };

  f32x4 acc[2][2];
#pragma unroll
  for (int a = 0; a < 2; ++a)
#pragma unroll
    for (int b = 0; b < 2; ++b) acc[a][b] = f32x4{0.f, 0.f, 0.f, 0.f};

  stg(0);
  FENCE();
  stg(8192);
  asm volatile("s_waitcnt vmcnt(4)" ::: "memory");
  __builtin_amdgcn_s_barrier();

  constexpr int NSTEP = KPAD / 64;  // 9
#pragma unroll
  for (int s = 0; s < NSTEP; ++s) {
    const int CB = (s & 1) * 8192;
    const unsigned short* sa = smem + CB;
    const unsigned short* sb = smem + CB + 4096;
    bf16x8 af[2][2], bf[2][2];
#pragma unroll
    for (int rg = 0; rg < 2; ++rg)
#pragma unroll
      for (int kh = 0; kh < 2; ++kh) {
        af[rg][kh] = *(const bf16x8*)(sa + (wm + rg * 16 + li) * 64 + (((kh * 4 + g) ^ swz) << 3));
        bf[rg][kh] = *(const bf16x8*)(sb + (wn + rg * 16 + li) * 64 + (((kh * 4 + g) ^ swz) << 3));
      }
    WAIT_LGKM0();
    __builtin_amdgcn_s_barrier();
    if (s + 2 < NSTEP) stg(CB);
    __builtin_amdgcn_s_setprio(1);
#pragma unroll
    for (int kh = 0; kh < 2; ++kh)
#pragma unroll
      for (int rg = 0; rg < 2; ++rg)
#pragma unroll
        for (int cg = 0; cg < 2; ++cg)
          acc[rg][cg] = MFMA32(af[rg][kh], bf[cg][kh], acc[rg][cg], 0, 0, 0);
    __builtin_amdgcn_s_setprio(0);
    if (s + 2 < NSTEP) {
      asm volatile("s_waitcnt vmcnt(4)" ::: "memory");
    } else if (s + 1 < NSTEP) {
      asm volatile("s_waitcnt vmcnt(0)" ::: "memory");
    }
    if (s + 1 < NSTEP) __builtin_amdgcn_s_barrier();
  }
  epi(acc, m0 + wm, n0 + wn, li, g);
}

// fused projection GEMM: z=0 Q (scaled), z=1 K, z=2 V (permuted vT layout)
// XCD-bijective remap: each XCD gets 8 consecutive m-blocks x all 27 (y,z)
// combos, so its L2 holds ~1.2 MB of A panels instead of all of posed (9.4 MB).
__global__ __launch_bounds__(256) void k_proj(const unsigned short* __restrict__ px,
                                              const unsigned short* __restrict__ py,
                                              const unsigned short* __restrict__ wq,
                                              const unsigned short* __restrict__ wk,
                                              const unsigned short* __restrict__ wv,
                                              unsigned short* __restrict__ qbuf,
                                              unsigned short* __restrict__ kbuf,
                                              unsigned short* __restrict__ vtb, float qsc) {
  __shared__ unsigned short smem[16384];
  // grid (64,9,3) = 1728 blocks; 1728 % 8 == 0 -> bijective chunked remap
  int lin = blockIdx.x + 64 * (blockIdx.y + 9 * blockIdx.z);
  int nl = (lin & 7) * 216 + (lin >> 3);
  int bx = (nl / 216) * 8 + (nl % 216) / 27;
  int yz = nl % 27;
  int by = yz % 9, z = yz / 9;
  if (z < 2 && by >= 8) return;

  const unsigned short* A = (z == 0) ? px : py;
  const unsigned short* BT = (z == 0) ? wq : (z == 1) ? wk : wv;

  gemm_core(A, BT, smem, bx * 64, by * 64,
            [&](f32x4 (&acc)[2][2], int mb, int nb, int li, int g) {
    if (z == 2) {  // vT permuted layout
#pragma unroll
      for (int rg = 0; rg < 2; ++rg) {
        int mr = mb + rg * 16 + 4 * g;
        int b = mr >> 11, seq0 = mr & 2047;
        int c0 = seq0 & 63;
        int npos = (seq0 & ~63) + ((c0 >> 2) & 3) * 16 + (c0 >> 4) * 4;
#pragma unroll
        for (int cg = 0; cg < 2; ++cg) {
          int col = nb + cg * 16 + li;
          int h = col >> 6, d = col & 63;
          ushort4 pk = make_ushort4(f2bf(acc[rg][cg][0]), f2bf(acc[rg][cg][1]),
                                    f2bf(acc[rg][cg][2]), f2bf(acc[rg][cg][3]));
          *(ushort4*)(vtb + (((size_t)b * 9 + h) * 64 + d) * 2048 + npos) = pk;
        }
      }
    } else {
      unsigned short* out = z ? kbuf : qbuf;
      float oscale = z ? 1.f : qsc;
#pragma unroll
      for (int rg = 0; rg < 2; ++rg) {
        int mr = mb + rg * 16 + 4 * g;
#pragma unroll
        for (int cg = 0; cg < 2; ++cg) {
          int col = nb + cg * 16 + li;
          int h = col >> 6, d = col & 63;
#pragma unroll
          for (int r = 0; r < 4; ++r) {
            int m = mr + r;
            int b = m >> 11, seq = m & 2047;
            out[(((size_t)b * 9 + h) * 2048 + seq) * 64 + d] = f2bf(acc[rg][cg][r] * oscale);
          }
        }
      }
    }
  });
}

// output GEMM with the same XCD-bijective remap (512 = 8 x 64 chunks)
__global__ __launch_bounds__(256) void k_gemm_out(const unsigned short* __restrict__ A,
                                                  const unsigned short* __restrict__ BT,
                                                  float* __restrict__ out, int Nout) {
  __shared__ unsigned short smem[16384];
  int lin = blockIdx.x + 64 * blockIdx.y;  // grid (64,8) = 512
  int nl = (lin & 7) * 64 + (lin >> 3);
  int bx = (nl / 64) * 8 + (nl % 64) / 8;
  int by = nl % 8;

  gemm_core(A, BT, smem, bx * 64, by * 64,
            [&](f32x4 (&acc)[2][2], int mb, int nb, int li, int g) {
#pragma unroll
    for (int rg = 0; rg < 2; ++rg) {
      int mr = mb + rg * 16 + 4 * g;
#pragma unroll
      for (int cg = 0; cg < 2; ++cg) {
        int col = nb + cg * 16 + li;
#pragma unroll
        for (int r = 0; r < 4; ++r) out[(size_t)(mr + r) * Nout + col] = acc[rg][cg][r];
      }
    }
  });
}

// ---------------- flash attention: QBLK=128, 4 waves x 2 u-groups, no-max softmax ----
// R12's exact kernel (best measured): counted-vmcnt pipeline, per-u transient
// QK/softmax, no-max softmax (shift-invariant; scale*log2e in Q), fp32 partials.
template <int NS>
__global__ __launch_bounds__(256) void k_attn(const unsigned short* __restrict__ qb,
                                              const unsigned short* __restrict__ kb,
                                              const unsigned short* __restrict__ vt,
                                              unsigned short* __restrict__ aout,
                                              float* __restrict__ pacc,
                                              float* __restrict__ pml) {
  constexpr int CH = 2048 / NS;
  constexpr int NT = CH / 64;
  constexpr int NBLK = 16 * 9 * 2 * NS;
  __shared__ unsigned short smem[16384];  // [0,8192): K dbuf ; [8192,16384): V dbuf

  int lin = blockIdx.x + 16 * (blockIdx.y + 9 * blockIdx.z);
  int nl = (lin & 7) * (NBLK / 8) + (lin >> 3);
  int bx = nl & 15;
  int rest = nl >> 4;
  int h = rest % 9;
  int z = rest / 9;
  int b = z / NS, sp = z - b * NS;

  const int wave = threadIdx.x >> 6, lane = threadIdx.x & 63;
  const int li = lane & 15, g = lane >> 4;
  const int bh = b * 9 + h;
  const int kvbase = sp * CH;
  const int swz = li & 7;

  // Q fragments (scale*log2e pre-folded): 2 groups of 16 rows
  bf16x8 qf[2][2];
#pragma unroll
  for (int u = 0; u < 2; ++u) {
    const unsigned short* qp =
        qb + ((size_t)bh * 2048 + bx * 128 + wave * 32 + u * 16 + li) * 64 + g * 8;
    qf[u][0] = *(const bf16x8*)qp;
    qf[u][1] = *(const bf16x8*)(qp + 32);
  }

  const int srow = threadIdx.x >> 3;
  const int ssc = (threadIdx.x & 7) ^ (srow & 7);
  const unsigned short* ksrc = kb + ((size_t)bh * 2048 + kvbase + srow) * 64 + ssc * 8;
  const unsigned short* vsrc = vt + ((size_t)bh * 64 + srow) * 2048 + kvbase + ssc * 8;

  auto stageK = [&](int bufOff) {
    gl_lds16(ksrc, (void*)(smem + bufOff + wave * 512));
    gl_lds16(ksrc + 32 * 64, (void*)(smem + bufOff + 2048 + wave * 512));
    ksrc += 64 * 64;
  };
  auto stageV = [&](int bufOff) {
    gl_lds16(vsrc, (void*)(smem + 8192 + bufOff + wave * 512));
    gl_lds16(vsrc + 32 * 2048, (void*)(smem + 8192 + bufOff + 2048 + wave * 512));
    vsrc += 64;
  };

  const unsigned short* kb0 = smem + li * 64 + ((g ^ swz) << 3);
  const unsigned short* kb1 = smem + li * 64 + (((4 + g) ^ swz) << 3);
  const unsigned short* vbE = smem + 8192 + li * 64 + (((2 * g) ^ swz) << 3);
  const unsigned short* vbO = smem + 8192 + li * 64 + (((2 * g + 1) ^ swz) << 3);

  float l_lane[2] = {0.f, 0.f};
  f32x4 acc[2][4];
#pragma unroll
  for (int u = 0; u < 2; ++u)
#pragma unroll
    for (int t = 0; t < 4; ++t) acc[u][t] = f32x4{0.f, 0.f, 0.f, 0.f};

  // prologue: 2 tiles in flight; vmcnt queue = K0,V0,K1,V1
  stageK(0);
  stageV(0);
  FENCE();
  stageK(4096);
  stageV(4096);
  asm volatile("s_waitcnt vmcnt(4)" ::: "memory");
  __builtin_amdgcn_s_barrier();

#pragma unroll
  for (int t = 0; t < NT; ++t) {
    const int CB = (t & 1) * 4096;

    // ---- K frags once per tile, then per-u QK + no-max softmax ----
    bf16x8 kA0[4], kA1[4];
#pragma unroll
    for (int tt = 0; tt < 4; ++tt) {
      kA0[tt] = *(const bf16x8*)(kb0 + CB + tt * 1024);
      kA1[tt] = *(const bf16x8*)(kb1 + CB + tt * 1024);
    }
    short4v p[2][4];
#pragma unroll
    for (int u = 0; u < 2; ++u) {
      f32x4 s[4];
      __builtin_amdgcn_s_setprio(1);
#pragma unroll
      for (int tt = 0; tt < 4; ++tt) {
        f32x4 sv = {0.f, 0.f, 0.f, 0.f};
        sv = MFMA32(kA0[tt], qf[u][0], sv, 0, 0, 0);
        sv = MFMA32(kA1[tt], qf[u][1], sv, 0, 0, 0);
        s[tt] = sv;
      }
      __builtin_amdgcn_s_setprio(0);
      float ts = 0.f;
#pragma unroll
      for (int tt = 0; tt < 4; ++tt) {
        float e0 = __builtin_amdgcn_exp2f(s[tt][0]);
        float e1 = __builtin_amdgcn_exp2f(s[tt][1]);
        float e2 = __builtin_amdgcn_exp2f(s[tt][2]);
        float e3 = __builtin_amdgcn_exp2f(s[tt][3]);
        ts += (e0 + e1) + (e2 + e3);
        p[u][tt] = pack_bf16x4(e0, e1, e2, e3);
      }
      l_lane[u] += ts;
    }
    WAIT_LGKM0();
    __builtin_amdgcn_s_barrier();  // all waves done reading K[CB]
    if (t + 2 < NT) stageK(CB);

    // ---- PV (permuted V layout) ----
    __builtin_amdgcn_s_setprio(1);
#pragma unroll
    for (int dd = 0; dd < 4; ++dd) {
      short8v ve = *(const short8v*)(vbE + CB + dd * 1024);
      short8v vo = *(const short8v*)(vbO + CB + dd * 1024);
      short4v v0 = __builtin_shufflevector(ve, ve, 0, 1, 2, 3);
      short4v v1 = __builtin_shufflevector(ve, ve, 4, 5, 6, 7);
      short4v v2 = __builtin_shufflevector(vo, vo, 0, 1, 2, 3);
      short4v v3 = __builtin_shufflevector(vo, vo, 4, 5, 6, 7);
#pragma unroll
      for (int u = 0; u < 2; ++u) {
        acc[u][dd] = MFMA16K(v0, p[u][0], acc[u][dd], 0, 0, 0);
        acc[u][dd] = MFMA16K(v1, p[u][1], acc[u][dd], 0, 0, 0);
        acc[u][dd] = MFMA16K(v2, p[u][2], acc[u][dd], 0, 0, 0);
        acc[u][dd] = MFMA16K(v3, p[u][3], acc[u][dd], 0, 0, 0);
      }
    }
    __builtin_amdgcn_s_setprio(0);
    WAIT_LGKM0();
    __builtin_amdgcn_s_barrier();  // all waves done reading V[CB]
    if (t + 2 < NT) stageV(CB);

    if (t + 2 < NT) {
      asm volatile("s_waitcnt vmcnt(4)" ::: "memory");
    } else if (t + 1 < NT) {
      asm volatile("s_waitcnt vmcnt(0)" ::: "memory");
    }
    if (t + 1 < NT) __builtin_amdgcn_s_barrier();
  }

#pragma unroll
  for (int u = 0; u < 2; ++u) {
    float lv = l_lane[u];
    lv += __shfl_xor(lv, 16);
    lv += __shfl_xor(lv, 32);
    if constexpr (NS == 1) {
      float inv = 1.f / lv;
      unsigned short* orow =
          aout + ((size_t)(b * 2048 + bx * 128 + wave * 32 + u * 16 + li)) * KPAD + h * 64;
#pragma unroll
      for (int t = 0; t < 4; ++t) {
        ushort4 pk = make_ushort4(f2bf(acc[u][t][0] * inv), f2bf(acc[u][t][1] * inv),
                                  f2bf(acc[u][t][2] * inv), f2bf(acc[u][t][3] * inv));
        *(ushort4*)(orow + t * 16 + 4 * g) = pk;
      }
    } else {
      int tile = bh * 128 + bx * 8 + wave * 2 + u;
      float* pa = pacc + ((size_t)tile * NS + sp) * 1024 + li * 64;
#pragma unroll
      for (int t = 0; t < 4; ++t) *(f32x4*)(pa + t * 16 + 4 * g) = acc[u][t];
      if (g == 0) {
        float2 st = make_float2(0.f, lv);
        *(float2*)(pml + ((size_t)tile * NS + sp) * 32 + li * 2) = st;
      }
    }
  }
}

// combine split-KV partials (plain sums; partials are exact softmax num/den)
__global__ __launch_bounds__(256) void k_combine(const float* __restrict__ pacc,
                                                 const float* __restrict__ pml,
                                                 unsigned short* __restrict__ aout, int NS) {
  int tile = blockIdx.x * 4 + (threadIdx.x >> 6);  // bh*128 + qt
  int bh = tile >> 7, qt = tile & 127;
  int b = bh / 9, h = bh - b * 9;
  int d = threadIdx.x & 63;
  for (int q = 0; q < 16; ++q) {
    const float* ml = pml + (size_t)tile * NS * 32 + q * 2;
    float num = 0.f, den = 0.f;
    const float* pa = pacc + (size_t)tile * NS * 1024 + q * 64 + d;
    for (int sp = 0; sp < NS; ++sp) {
      den += ml[sp * 32 + 1];
      num += pa[(size_t)sp * 1024];
    }
    aout[((size_t)(b * 2048 + qt * 16 + q)) * KPAD + h * 64 + d] = f2bf(num / den);
  }
}

// ---------------- launch ----------------

extern "C" void kernel_launch(void* const* d_in, const int* in_sizes, int n_in,
                              void* d_out, int out_size, void* d_ws, size_t ws_size,
                              hipStream_t stream) {
  const float* x  = (const float*)d_in[0];
  const float* y  = (const float*)d_in[1];
  const float* cx = (const float*)d_in[2];
  const float* cy = (const float*)d_in[3];
  const float* Wq = (const float*)d_in[4];
  const float* Wk = (const float*)d_in[5];
  const float* Wv = (const float*)d_in[6];
  const float* Wo = (const float*)d_in[7];
  const float* cs = (const float*)d_in[8];

  char* w = (char*)d_ws;
  auto take = [&](size_t bytes) {
    char* p = w;
    w += (bytes + 255) & ~(size_t)255;
    return p;
  };
  unsigned short* posed_x = (unsigned short*)take((size_t)4096 * KPAD * 2);
  unsigned short* posed_y = (unsigned short*)take((size_t)4096 * KPAD * 2);
  unsigned short* wqT = (unsigned short*)take((size_t)512 * KPAD * 2);
  unsigned short* wkT = (unsigned short*)take((size_t)512 * KPAD * 2);
  unsigned short* wvT = (unsigned short*)take((size_t)576 * KPAD * 2);
  unsigned short* woT = (unsigned short*)take((size_t)512 * KPAD * 2);
  unsigned short* qbuf = (unsigned short*)take((size_t)2 * 9 * 2048 * 64 * 2);
  unsigned short* kbuf = (unsigned short*)take((size_t)2 * 9 * 2048 * 64 * 2);
  unsigned short* vtb  = (unsigned short*)take((size_t)2 * 9 * 64 * 2048 * 2);
  unsigned short* aout = (unsigned short*)take((size_t)4096 * KPAD * 2);

  size_t base_used = (size_t)(w - (char*)d_ws);
  auto fits = [&](int ns) {
    return base_used + (size_t)2304 * ns * (1024 + 32) * 4 + 1024 <= ws_size;
  };
  int NS = fits(4) ? 4 : (fits(2) ? 2 : 1);
  float* pacc = nullptr;
  float* pml = nullptr;
  if (NS > 1) {
    pacc = (float*)take((size_t)2304 * NS * 1024 * 4);
    pml  = (float*)take((size_t)2304 * NS * 32 * 4);
  }

  // posed_x is the base of a contiguous [8192, KPAD] region (posed_x then posed_y)
  k_pack_all<<<6416, 256, 0, stream>>>(x, cx, y, cy, Wq, Wk, Wv, Wo,
                                       posed_x, wqT, wkT, wvT, woT, qbuf, kbuf, cs);

  const float qsc = 0.125f * LOG2E;
  k_proj<<<dim3(64, 9, 3), 256, 0, stream>>>(posed_x, posed_y, wqT, wkT, wvT,
                                             qbuf, kbuf, vtb, qsc);

  dim3 ga(16, 9, 2 * NS);
  if (NS == 4)      k_attn<4><<<ga, 256, 0, stream>>>(qbuf, kbuf, vtb, aout, pacc, pml);
  else if (NS == 2) k_attn<2><<<ga, 256, 0, stream>>>(qbuf, kbuf, vtb, aout, pacc, pml);
  else              k_attn<1><<<ga, 256, 0, stream>>>(qbuf, kbuf, vtb, aout, pacc, pml);
  if (NS > 1) k_combine<<<576, 256, 0, stream>>>(pacc, pml, aout, NS);

  k_gemm_out<<<dim3(64, 8), 256, 0, stream>>>(aout, woT, (float*)d_out, 512);
}

// Round 18
// 74.407 us; speedup vs baseline: 1.3739x; 1.1792x over previous
//
#include <hip/hip_runtime.h>

typedef __bf16 bf16x8 __attribute__((ext_vector_type(8)));
typedef short short4v __attribute__((ext_vector_type(4)));
typedef short short8v __attribute__((ext_vector_type(8)));
typedef float f32x4 __attribute__((ext_vector_type(4)));

#define MFMA32 __builtin_amdgcn_mfma_f32_16x16x32_bf16
#define MFMA16K __builtin_amdgcn_mfma_f32_16x16x16bf16_1k

#define KPAD 576
#define LOG2E 1.44269504f

__device__ __forceinline__ unsigned short f2bf(float f) {
  unsigned u = __float_as_uint(f);
  u += 0x7FFFu + ((u >> 16) & 1u);
  return (unsigned short)(u >> 16);
}

__device__ __forceinline__ unsigned cvtpk_bf16(float a, float b) {
  unsigned r;
  asm("v_cvt_pk_bf16_f32 %0, %1, %2" : "=v"(r) : "v"(a), "v"(b));
  return r;  // lo = bf16(a), hi = bf16(b)
}

__device__ __forceinline__ short4v pack_bf16x4(float e0, float e1, float e2, float e3) {
  union { unsigned u[2]; short4v s; } pu;
  pu.u[0] = cvtpk_bf16(e0, e1);
  pu.u[1] = cvtpk_bf16(e2, e3);
  return pu.s;
}

__device__ __forceinline__ void gl_lds16(const void* g, void* l) {
  __builtin_amdgcn_global_load_lds((const __attribute__((address_space(1))) unsigned int*)g,
                                   (__attribute__((address_space(3))) unsigned int*)l, 16, 0, 0);
}

#define FENCE() asm volatile("" ::: "memory")
#define WAIT_LGKM0() do { asm volatile("s_waitcnt lgkmcnt(0)" ::: "memory"); \
                          __builtin_amdgcn_sched_barrier(0); } while (0)

// ---------------- fused pack kernel (posed | weightT | coord-head) ----------------
__global__ __launch_bounds__(256) void k_pack_all(
    const float* __restrict__ x, const float* __restrict__ cx,
    const float* __restrict__ y, const float* __restrict__ cy,
    const float* __restrict__ Wq, const float* __restrict__ Wk,
    const float* __restrict__ Wv, const float* __restrict__ Wo,
    unsigned short* __restrict__ posed, unsigned short* __restrict__ wqT,
    unsigned short* __restrict__ wkT, unsigned short* __restrict__ wvT,
    unsigned short* __restrict__ woT, unsigned short* __restrict__ qbuf,
    unsigned short* __restrict__ kbuf, const float* __restrict__ cs) {
  __shared__ unsigned short tile[32][33];
  int blk = blockIdx.x;
  if (blk < 4608) {  // posed: rows 0..4095 = (x,cx), 4096..8191 = (y,cy)
    int i = blk * 256 + threadIdx.x;  // 8192 * 144 groups of 4 cols
    int r = i / (KPAD / 4), c = (i - r * (KPAD / 4)) * 4;
    const float* feat = (r < 4096) ? x : y;
    const float* coord = (r < 4096) ? cx : cy;
    int rr = r & 4095;
    float4 v = {0.f, 0.f, 0.f, 0.f};
    if (c < 512) v = *(const float4*)(feat + (size_t)rr * 512 + c);
    else if (c == 512) {
      v.x = coord[(size_t)rr * 3];
      v.y = coord[(size_t)rr * 3 + 1];
      v.z = coord[(size_t)rr * 3 + 2];
    }
    ushort4 o = make_ushort4(f2bf(v.x), f2bf(v.y), f2bf(v.z), f2bf(v.w));
    *(ushort4*)(posed + (size_t)i * 4) = o;
  } else if (blk < 5904) {  // weight transpose: 4 matrices x 18 x 18 tiles
    int local = blk - 4608;
    int z = local / 324, rem = local % 324;
    int gy = rem / 18, gx = rem % 18;
    int nout = (z == 2) ? 576 : 512;
    if (gy * 32 >= nout) return;
    int kin = (z == 3) ? 576 : 515;
    const float* w = (z == 0) ? Wq : (z == 1) ? Wk : (z == 2) ? Wv : Wo;
    unsigned short* dst = (z == 0) ? wqT : (z == 1) ? wkT : (z == 2) ? wvT : woT;
    int kc0 = gx * 32, n0 = gy * 32;
    int tx = threadIdx.x & 31, ty = threadIdx.x >> 5;  // 32 x 8
#pragma unroll
    for (int it = 0; it < 4; ++it) {
      int kc = kc0 + ty + it * 8;
      float v = (kc < kin) ? w[(size_t)kc * nout + n0 + tx] : 0.f;
      tile[ty + it * 8][tx] = f2bf(v);
    }
    __syncthreads();
#pragma unroll
    for (int it = 0; it < 4; ++it) {
      int n = n0 + ty + it * 8;
      dst[(size_t)n * KPAD + kc0 + tx] = tile[tx][ty + it * 8];
    }
  } else {  // coord head (h=8) of q/k buffers
    int i = (blk - 5904) * 256 + threadIdx.x;  // 8192 rows * 16 groups of 4
    int rr = i >> 4, d4 = (i & 15) * 4;
    int qside = rr < 4096;
    int row = rr & 4095;
    const float* coord = qside ? cx : cy;
    unsigned short* buf = qside ? qbuf : kbuf;
    int b = row >> 11, n = row & 2047;
    ushort4 o = make_ushort4(0, 0, 0, 0);
    if (d4 == 0) {
      float sc = qside ? cs[0] * LOG2E : 1.f;
      o.x = f2bf(coord[(size_t)row * 3] * sc);
      o.y = f2bf(coord[(size_t)row * 3 + 1] * sc);
      o.z = f2bf(coord[(size_t)row * 3 + 2] * sc);
    }
    *(ushort4*)(buf + (((size_t)b * 9 + 8) * 2048 + n) * 64 + d4) = o;
  }
}

// ---------------- GEMM core: 64x64 block, 4 waves, 32x32 wave tile ----------------
template <typename EPI>
__device__ __forceinline__ void gemm_core(const unsigned short* __restrict__ A,
                                          const unsigned short* __restrict__ BT,
                                          unsigned short* smem, int m0, int n0, EPI epi) {
  const int tid = threadIdx.x;
  const int wave = tid >> 6, lane = tid & 63;
  const int li = lane & 15, g = lane >> 4;
  const int wm = (wave & 1) * 32;
  const int wn = (wave >> 1) * 32;
  const int swz = li & 7;

  const int srow = tid >> 3, sc = (tid & 7) ^ (srow & 7);
  const unsigned short* asrc = A + (size_t)(m0 + srow) * KPAD + sc * 8;
  const unsigned short* bsrc = BT + (size_t)(n0 + srow) * KPAD + sc * 8;

  auto stg = [&](int bufOff) {
    gl_lds16(asrc, (void*)(smem + bufOff + wave * 512));
    gl_lds16(asrc + (size_t)32 * KPAD, (void*)(smem + bufOff + 2048 + wave * 512));
    gl_lds16(bsrc, (void*)(smem + bufOff + 4096 + wave * 512));
    gl_lds16(bsrc + (size_t)32 * KPAD, (void*)(smem + bufOff + 4096 + 2048 + wave * 512));
    asrc += 64;
    bsrc += 64;
  };

  f32x4 acc[2][2];
#pragma unroll
  for (int a = 0; a < 2; ++a)
#pragma unroll
    for (int b = 0; b < 2; ++b) acc[a][b] = f32x4{0.f, 0.f, 0.f, 0.f};

  stg(0);
  FENCE();
  stg(8192);
  asm volatile("s_waitcnt vmcnt(4)" ::: "memory");
  __builtin_amdgcn_s_barrier();

  constexpr int NSTEP = KPAD / 64;  // 9
#pragma unroll
  for (int s = 0; s < NSTEP; ++s) {
    const int CB = (s & 1) * 8192;
    const unsigned short* sa = smem + CB;
    const unsigned short* sb = smem + CB + 4096;
    bf16x8 af[2][2], bf[2][2];
#pragma unroll
    for (int rg = 0; rg < 2; ++rg)
#pragma unroll
      for (int kh = 0; kh < 2; ++kh) {
        af[rg][kh] = *(const bf16x8*)(sa + (wm + rg * 16 + li) * 64 + (((kh * 4 + g) ^ swz) << 3));
        bf[rg][kh] = *(const bf16x8*)(sb + (wn + rg * 16 + li) * 64 + (((kh * 4 + g) ^ swz) << 3));
      }
    WAIT_LGKM0();
    __builtin_amdgcn_s_barrier();
    if (s + 2 < NSTEP) stg(CB);
    __builtin_amdgcn_s_setprio(1);
#pragma unroll
    for (int kh = 0; kh < 2; ++kh)
#pragma unroll
      for (int rg = 0; rg < 2; ++rg)
#pragma unroll
        for (int cg = 0; cg < 2; ++cg)
          acc[rg][cg] = MFMA32(af[rg][kh], bf[cg][kh], acc[rg][cg], 0, 0, 0);
    __builtin_amdgcn_s_setprio(0);
    if (s + 2 < NSTEP) {
      asm volatile("s_waitcnt vmcnt(4)" ::: "memory");
    } else if (s + 1 < NSTEP) {
      asm volatile("s_waitcnt vmcnt(0)" ::: "memory");
    }
    if (s + 1 < NSTEP) __builtin_amdgcn_s_barrier();
  }
  epi(acc, m0 + wm, n0 + wn, li, g);
}

// fused projection GEMM: z=0 Q (scaled), z=1 K, z=2 V (permuted vT layout)
__global__ __launch_bounds__(256) void k_proj(const unsigned short* __restrict__ px,
                                              const unsigned short* __restrict__ py,
                                              const unsigned short* __restrict__ wq,
                                              const unsigned short* __restrict__ wk,
                                              const unsigned short* __restrict__ wv,
                                              unsigned short* __restrict__ qbuf,
                                              unsigned short* __restrict__ kbuf,
                                              unsigned short* __restrict__ vtb, float qsc) {
  __shared__ unsigned short smem[16384];
  // grid (64,9,3) = 1728 blocks; 1728 % 8 == 0 -> bijective chunked remap
  int lin = blockIdx.x + 64 * (blockIdx.y + 9 * blockIdx.z);
  int nl = (lin & 7) * 216 + (lin >> 3);
  int bx = (nl / 216) * 8 + (nl % 216) / 27;
  int yz = nl % 27;
  int by = yz % 9, z = yz / 9;
  if (z < 2 && by >= 8) return;

  const unsigned short* A = (z == 0) ? px : py;
  const unsigned short* BT = (z == 0) ? wq : (z == 1) ? wk : wv;

  gemm_core(A, BT, smem, bx * 64, by * 64,
            [&](f32x4 (&acc)[2][2], int mb, int nb, int li, int g) {
    if (z == 2) {  // vT permuted layout
#pragma unroll
      for (int rg = 0; rg < 2; ++rg) {
        int mr = mb + rg * 16 + 4 * g;
        int b = mr >> 11, seq0 = mr & 2047;
        int c0 = seq0 & 63;
        int npos = (seq0 & ~63) + ((c0 >> 2) & 3) * 16 + (c0 >> 4) * 4;
#pragma unroll
        for (int cg = 0; cg < 2; ++cg) {
          int col = nb + cg * 16 + li;
          int h = col >> 6, d = col & 63;
          ushort4 pk = make_ushort4(f2bf(acc[rg][cg][0]), f2bf(acc[rg][cg][1]),
                                    f2bf(acc[rg][cg][2]), f2bf(acc[rg][cg][3]));
          *(ushort4*)(vtb + (((size_t)b * 9 + h) * 64 + d) * 2048 + npos) = pk;
        }
      }
    } else {
      unsigned short* out = z ? kbuf : qbuf;
      float oscale = z ? 1.f : qsc;
#pragma unroll
      for (int rg = 0; rg < 2; ++rg) {
        int mr = mb + rg * 16 + 4 * g;
#pragma unroll
        for (int cg = 0; cg < 2; ++cg) {
          int col = nb + cg * 16 + li;
          int h = col >> 6, d = col & 63;
#pragma unroll
          for (int r = 0; r < 4; ++r) {
            int m = mr + r;
            int b = m >> 11, seq = m & 2047;
            out[(((size_t)b * 9 + h) * 2048 + seq) * 64 + d] = f2bf(acc[rg][cg][r] * oscale);
          }
        }
      }
    }
  });
}

// output GEMM with the same XCD-bijective remap (512 = 8 x 64 chunks)
__global__ __launch_bounds__(256) void k_gemm_out(const unsigned short* __restrict__ A,
                                                  const unsigned short* __restrict__ BT,
                                                  float* __restrict__ out, int Nout) {
  __shared__ unsigned short smem[16384];
  int lin = blockIdx.x + 64 * blockIdx.y;  // grid (64,8) = 512
  int nl = (lin & 7) * 64 + (lin >> 3);
  int bx = (nl / 64) * 8 + (nl % 64) / 8;
  int by = nl % 8;

  gemm_core(A, BT, smem, bx * 64, by * 64,
            [&](f32x4 (&acc)[2][2], int mb, int nb, int li, int g) {
#pragma unroll
    for (int rg = 0; rg < 2; ++rg) {
      int mr = mb + rg * 16 + 4 * g;
#pragma unroll
      for (int cg = 0; cg < 2; ++cg) {
        int col = nb + cg * 16 + li;
#pragma unroll
        for (int r = 0; r < 4; ++r) out[(size_t)(mr + r) * Nout + col] = acc[rg][cg][r];
      }
    }
  });
}

// ---------------- flash attention: QBLK=128, 4 waves x 2 u-groups, no-max softmax ----
// R12's exact kernel (best measured): counted-vmcnt pipeline, per-u transient
// QK/softmax, no-max softmax (shift-invariant; scale*log2e in Q), fp32 partials.
template <int NS>
__global__ __launch_bounds__(256) void k_attn(const unsigned short* __restrict__ qb,
                                              const unsigned short* __restrict__ kb,
                                              const unsigned short* __restrict__ vt,
                                              unsigned short* __restrict__ aout,
                                              float* __restrict__ pacc,
                                              float* __restrict__ pml) {
  constexpr int CH = 2048 / NS;
  constexpr int NT = CH / 64;
  constexpr int NBLK = 16 * 9 * 2 * NS;
  __shared__ unsigned short smem[16384];  // [0,8192): K dbuf ; [8192,16384): V dbuf

  int lin = blockIdx.x + 16 * (blockIdx.y + 9 * blockIdx.z);
  int nl = (lin & 7) * (NBLK / 8) + (lin >> 3);
  int bx = nl & 15;
  int rest = nl >> 4;
  int h = rest % 9;
  int z = rest / 9;
  int b = z / NS, sp = z - b * NS;

  const int wave = threadIdx.x >> 6, lane = threadIdx.x & 63;
  const int li = lane & 15, g = lane >> 4;
  const int bh = b * 9 + h;
  const int kvbase = sp * CH;
  const int swz = li & 7;

  // Q fragments (scale*log2e pre-folded): 2 groups of 16 rows
  bf16x8 qf[2][2];
#pragma unroll
  for (int u = 0; u < 2; ++u) {
    const unsigned short* qp =
        qb + ((size_t)bh * 2048 + bx * 128 + wave * 32 + u * 16 + li) * 64 + g * 8;
    qf[u][0] = *(const bf16x8*)qp;
    qf[u][1] = *(const bf16x8*)(qp + 32);
  }

  const int srow = threadIdx.x >> 3;
  const int ssc = (threadIdx.x & 7) ^ (srow & 7);
  const unsigned short* ksrc = kb + ((size_t)bh * 2048 + kvbase + srow) * 64 + ssc * 8;
  const unsigned short* vsrc = vt + ((size_t)bh * 64 + srow) * 2048 + kvbase + ssc * 8;

  auto stageK = [&](int bufOff) {
    gl_lds16(ksrc, (void*)(smem + bufOff + wave * 512));
    gl_lds16(ksrc + 32 * 64, (void*)(smem + bufOff + 2048 + wave * 512));
    ksrc += 64 * 64;
  };
  auto stageV = [&](int bufOff) {
    gl_lds16(vsrc, (void*)(smem + 8192 + bufOff + wave * 512));
    gl_lds16(vsrc + 32 * 2048, (void*)(smem + 8192 + bufOff + 2048 + wave * 512));
    vsrc += 64;
  };

  const unsigned short* kb0 = smem + li * 64 + ((g ^ swz) << 3);
  const unsigned short* kb1 = smem + li * 64 + (((4 + g) ^ swz) << 3);
  const unsigned short* vbE = smem + 8192 + li * 64 + (((2 * g) ^ swz) << 3);
  const unsigned short* vbO = smem + 8192 + li * 64 + (((2 * g + 1) ^ swz) << 3);

  float l_lane[2] = {0.f, 0.f};
  f32x4 acc[2][4];
#pragma unroll
  for (int u = 0; u < 2; ++u)
#pragma unroll
    for (int t = 0; t < 4; ++t) acc[u][t] = f32x4{0.f, 0.f, 0.f, 0.f};

  // prologue: 2 tiles in flight; vmcnt queue = K0,V0,K1,V1
  stageK(0);
  stageV(0);
  FENCE();
  stageK(4096);
  stageV(4096);
  asm volatile("s_waitcnt vmcnt(4)" ::: "memory");
  __builtin_amdgcn_s_barrier();

#pragma unroll
  for (int t = 0; t < NT; ++t) {
    const int CB = (t & 1) * 4096;

    // ---- K frags once per tile, then per-u QK + no-max softmax ----
    bf16x8 kA0[4], kA1[4];
#pragma unroll
    for (int tt = 0; tt < 4; ++tt) {
      kA0[tt] = *(const bf16x8*)(kb0 + CB + tt * 1024);
      kA1[tt] = *(const bf16x8*)(kb1 + CB + tt * 1024);
    }
    short4v p[2][4];
#pragma unroll
    for (int u = 0; u < 2; ++u) {
      f32x4 s[4];
      __builtin_amdgcn_s_setprio(1);
#pragma unroll
      for (int tt = 0; tt < 4; ++tt) {
        f32x4 sv = {0.f, 0.f, 0.f, 0.f};
        sv = MFMA32(kA0[tt], qf[u][0], sv, 0, 0, 0);
        sv = MFMA32(kA1[tt], qf[u][1], sv, 0, 0, 0);
        s[tt] = sv;
      }
      __builtin_amdgcn_s_setprio(0);
      float ts = 0.f;
#pragma unroll
      for (int tt = 0; tt < 4; ++tt) {
        float e0 = __builtin_amdgcn_exp2f(s[tt][0]);
        float e1 = __builtin_amdgcn_exp2f(s[tt][1]);
        float e2 = __builtin_amdgcn_exp2f(s[tt][2]);
        float e3 = __builtin_amdgcn_exp2f(s[tt][3]);
        ts += (e0 + e1) + (e2 + e3);
        p[u][tt] = pack_bf16x4(e0, e1, e2, e3);
      }
      l_lane[u] += ts;
    }
    WAIT_LGKM0();
    __builtin_amdgcn_s_barrier();  // all waves done reading K[CB]
    if (t + 2 < NT) stageK(CB);

    // ---- PV (permuted V layout) ----
    __builtin_amdgcn_s_setprio(1);
#pragma unroll
    for (int dd = 0; dd < 4; ++dd) {
      short8v ve = *(const short8v*)(vbE + CB + dd * 1024);
      short8v vo = *(const short8v*)(vbO + CB + dd * 1024);
      short4v v0 = __builtin_shufflevector(ve, ve, 0, 1, 2, 3);
      short4v v1 = __builtin_shufflevector(ve, ve, 4, 5, 6, 7);
      short4v v2 = __builtin_shufflevector(vo, vo, 0, 1, 2, 3);
      short4v v3 = __builtin_shufflevector(vo, vo, 4, 5, 6, 7);
#pragma unroll
      for (int u = 0; u < 2; ++u) {
        acc[u][dd] = MFMA16K(v0, p[u][0], acc[u][dd], 0, 0, 0);
        acc[u][dd] = MFMA16K(v1, p[u][1], acc[u][dd], 0, 0, 0);
        acc[u][dd] = MFMA16K(v2, p[u][2], acc[u][dd], 0, 0, 0);
        acc[u][dd] = MFMA16K(v3, p[u][3], acc[u][dd], 0, 0, 0);
      }
    }
    __builtin_amdgcn_s_setprio(0);
    WAIT_LGKM0();
    __builtin_amdgcn_s_barrier();  // all waves done reading V[CB]
    if (t + 2 < NT) stageV(CB);

    if (t + 2 < NT) {
      asm volatile("s_waitcnt vmcnt(4)" ::: "memory");
    } else if (t + 1 < NT) {
      asm volatile("s_waitcnt vmcnt(0)" ::: "memory");
    }
    if (t + 1 < NT) __builtin_amdgcn_s_barrier();
  }

#pragma unroll
  for (int u = 0; u < 2; ++u) {
    float lv = l_lane[u];
    lv += __shfl_xor(lv, 16);
    lv += __shfl_xor(lv, 32);
    if constexpr (NS == 1) {
      float inv = 1.f / lv;
      unsigned short* orow =
          aout + ((size_t)(b * 2048 + bx * 128 + wave * 32 + u * 16 + li)) * KPAD + h * 64;
#pragma unroll
      for (int t = 0; t < 4; ++t) {
        ushort4 pk = make_ushort4(f2bf(acc[u][t][0] * inv), f2bf(acc[u][t][1] * inv),
                                  f2bf(acc[u][t][2] * inv), f2bf(acc[u][t][3] * inv));
        *(ushort4*)(orow + t * 16 + 4 * g) = pk;
      }
    } else {
      int tile = bh * 128 + bx * 8 + wave * 2 + u;
      float* pa = pacc + ((size_t)tile * NS + sp) * 1024 + li * 64;
#pragma unroll
      for (int t = 0; t < 4; ++t) *(f32x4*)(pa + t * 16 + 4 * g) = acc[u][t];
      if (g == 0) {
        float2 st = make_float2(0.f, lv);
        *(float2*)(pml + ((size_t)tile * NS + sp) * 32 + li * 2) = st;
      }
    }
  }
}

// combine split-KV partials, vectorized: each wave owns one tile; per (w4, sp)
// the wave reads a 1 KB contiguous f32x4 slab (64 lanes x 16B). q = w4*4+(lane>>4),
// d = (lane&15)*4 + i  — pure bijection of the scalar loop (same math, same sums).
__global__ __launch_bounds__(256) void k_combine(const float* __restrict__ pacc,
                                                 const float* __restrict__ pml,
                                                 unsigned short* __restrict__ aout, int NS) {
  int tile = blockIdx.x * 4 + (threadIdx.x >> 6);  // bh*128 + qt
  int bh = tile >> 7, qt = tile & 127;
  int b = bh / 9, h = bh - b * 9;
  int lane = threadIdx.x & 63;
  const float* pbase = pacc + (size_t)tile * NS * 1024 + lane * 4;
  const float* mlbase = pml + (size_t)tile * NS * 32 + (lane >> 4) * 2 + 1;
#pragma unroll
  for (int w4 = 0; w4 < 4; ++w4) {
    int q = w4 * 4 + (lane >> 4);
    f32x4 num = {0.f, 0.f, 0.f, 0.f};
    float den = 0.f;
    for (int sp = 0; sp < NS; ++sp) {
      num += *(const f32x4*)(pbase + (size_t)sp * 1024 + w4 * 256);
      den += mlbase[sp * 32 + w4 * 8];  // pml[.. + q*2 + 1], q = w4*4 + (lane>>4)
    }
    float inv = 1.f / den;
    ushort4 pk = make_ushort4(f2bf(num[0] * inv), f2bf(num[1] * inv),
                              f2bf(num[2] * inv), f2bf(num[3] * inv));
    *(ushort4*)(aout + ((size_t)(b * 2048 + qt * 16 + q)) * KPAD + h * 64 + (lane & 15) * 4) = pk;
  }
}

// ---------------- launch ----------------

extern "C" void kernel_launch(void* const* d_in, const int* in_sizes, int n_in,
                              void* d_out, int out_size, void* d_ws, size_t ws_size,
                              hipStream_t stream) {
  const float* x  = (const float*)d_in[0];
  const float* y  = (const float*)d_in[1];
  const float* cx = (const float*)d_in[2];
  const float* cy = (const float*)d_in[3];
  const float* Wq = (const float*)d_in[4];
  const float* Wk = (const float*)d_in[5];
  const float* Wv = (const float*)d_in[6];
  const float* Wo = (const float*)d_in[7];
  const float* cs = (const float*)d_in[8];

  char* w = (char*)d_ws;
  auto take = [&](size_t bytes) {
    char* p = w;
    w += (bytes + 255) & ~(size_t)255;
    return p;
  };
  unsigned short* posed_x = (unsigned short*)take((size_t)4096 * KPAD * 2);
  unsigned short* posed_y = (unsigned short*)take((size_t)4096 * KPAD * 2);
  unsigned short* wqT = (unsigned short*)take((size_t)512 * KPAD * 2);
  unsigned short* wkT = (unsigned short*)take((size_t)512 * KPAD * 2);
  unsigned short* wvT = (unsigned short*)take((size_t)576 * KPAD * 2);
  unsigned short* woT = (unsigned short*)take((size_t)512 * KPAD * 2);
  unsigned short* qbuf = (unsigned short*)take((size_t)2 * 9 * 2048 * 64 * 2);
  unsigned short* kbuf = (unsigned short*)take((size_t)2 * 9 * 2048 * 64 * 2);
  unsigned short* vtb  = (unsigned short*)take((size_t)2 * 9 * 64 * 2048 * 2);
  unsigned short* aout = (unsigned short*)take((size_t)4096 * KPAD * 2);

  size_t base_used = (size_t)(w - (char*)d_ws);
  auto fits = [&](int ns) {
    return base_used + (size_t)2304 * ns * (1024 + 32) * 4 + 1024 <= ws_size;
  };
  int NS = fits(4) ? 4 : (fits(2) ? 2 : 1);
  float* pacc = nullptr;
  float* pml = nullptr;
  if (NS > 1) {
    pacc = (float*)take((size_t)2304 * NS * 1024 * 4);
    pml  = (float*)take((size_t)2304 * NS * 32 * 4);
  }

  // posed_x is the base of a contiguous [8192, KPAD] region (posed_x then posed_y)
  k_pack_all<<<6416, 256, 0, stream>>>(x, cx, y, cy, Wq, Wk, Wv, Wo,
                                       posed_x, wqT, wkT, wvT, woT, qbuf, kbuf, cs);

  const float qsc = 0.125f * LOG2E;
  k_proj<<<dim3(64, 9, 3), 256, 0, stream>>>(posed_x, posed_y, wqT, wkT, wvT,
                                             qbuf, kbuf, vtb, qsc);

  dim3 ga(16, 9, 2 * NS);
  if (NS == 4)      k_attn<4><<<ga, 256, 0, stream>>>(qbuf, kbuf, vtb, aout, pacc, pml);
  else if (NS == 2) k_attn<2><<<ga, 256, 0, stream>>>(qbuf, kbuf, vtb, aout, pacc, pml);
  else              k_attn<1><<<ga, 256, 0, stream>>>(qbuf, kbuf, vtb, aout, pacc, pml);
  if (NS > 1) k_combine<<<576, 256, 0, stream>>>(pacc, pml, aout, NS);

  k_gemm_out<<<dim3(64, 8), 256, 0, stream>>>(aout, woT, (float*)d_out, 512);
}